// Round 7
// baseline (917.970 us; speedup 1.0000x reference)
//
#include <hip/hip_runtime.h>
#include <hip/hip_bf16.h>
#include <hip/hip_fp16.h>
#include <math.h>

#define Lq 512
#define CSd 256
#define CZd 128
#define Hd 8
#define CHd 32
#define PQd 4
#define PVd 8
#define CATd 1536
#define NPROJ 1152

typedef __attribute__((ext_vector_type(4))) float floatx4;
typedef __attribute__((ext_vector_type(8))) short shortx8;

// ---------------- ws layout (float offsets) ----------------
#define OFF_SC      0         // 131072
#define OFF_PB      393216    // 1048576 (half)
#define OFF_P       1441792   // 589824  (P, then reused as 4 ipa planes 4*131072)
#define OFF_QN      2031616   // 4096
#define OFF_KN      2035712   // 4096
#define OFF_A16     2039808   // 2097152 (a16hi only)
#define OFF_CAT     4136960   // 786432 floats = catA16: hi plane 786432 shorts + lo plane
#define OFF_S0      4923392   // 131072
#define OFF_R       5054464   // 4608
#define OFF_T       5059072   // 1536
#define OFF_GAMMA   5060608   // 8
#define OFF_MASKB   5060616   // 512
#define OFF_BCAT    5061128   // 1152
#define OFF_WINITP  5062280   // 65536
#define OFF_WT1P    5127816   // 65536
#define OFF_WT2P    5193352   // 65536
#define OFF_WT3P    5258888   // 65536
#define OFF_WOP     5324424   // 393216
#define OFF_WCATP   5717640   // 294912
#define OFF_QP      6012552   // 262144 (fp32)
#define OFF_KP      6274696   // 262144 (=524288 bf16)
#define OFF_VP      6536840   // 262144 (=524288 bf16)
#define OFF_SCA16   6798984   // 131072 (=262144 shorts: hi plane 131072 + lo plane)
#define OFF_ZNT     6930056   // 16777216 (=33554432 bf16)  [i][c][j]

#define CAT_LO 786432

#define WLC 0.57735026918962576f
#define WCC 0.23570226039551584f
#define ISC 0.17677669529663687f

__device__ __forceinline__ float wave_sum(float v){
  #pragma unroll
  for (int m=32; m; m>>=1) v += __shfl_xor(v, m);
  return v;
}
__device__ __forceinline__ short f2bf(float v){
  __hip_bfloat16 h = (__hip_bfloat16)v;
  return __builtin_bit_cast(short, h);
}
__device__ __forceinline__ float bf2f(short s){
  unsigned u = ((unsigned)(unsigned short)s) << 16;
  return __builtin_bit_cast(float, u);
}
__device__ __forceinline__ __hip_bfloat16 s2b(short s){
  return __builtin_bit_cast(__hip_bfloat16, s);
}
// store one (row, col k) element of cat in MFMA-A hi/lo fragment layout
__device__ __forceinline__ void cat_store(short* __restrict__ catA16, int k, int row, float v){
  size_t off = (((size_t)(k>>5)*512 + row)*4 + ((k>>3)&3))*8 + (k&7);
  short hh = f2bf(v);
  catA16[off]          = hh;
  catA16[off + CAT_LO] = f2bf(v - bf2f(hh));
}

// ------------- setup -------------
__global__ __launch_bounds__(256) void k_setup(
    const float* __restrict__ bq, const float* __restrict__ bk, const float* __restrict__ bv,
    const float* __restrict__ bqp, const float* __restrict__ bkp, const float* __restrict__ bvp,
    const float* __restrict__ head_w, const float* __restrict__ mask,
    float* __restrict__ bcat, float* __restrict__ gamma,
    float* __restrict__ maskb, float* __restrict__ R, float* __restrict__ t){
  int k = blockIdx.x*256 + threadIdx.x;
  if (k < NPROJ){
    float v;
    if      (k < 256) v = bq[k];
    else if (k < 512) v = bk[k-256];
    else if (k < 768) v = bv[k-512];
    else if (k < 864) v = bqp[k-768];
    else if (k < 960) v = bkp[k-864];
    else              v = bvp[k-960];
    bcat[k] = v;
    return;
  }
  k -= NPROJ;
  if (k < Hd){ gamma[k] = log1pf(expf(head_w[k])); return; }
  k -= Hd;
  if (k < Lq){ maskb[k] = (mask[k] - 1.f)*1e9f; return; }
  k -= Lq;
  if (k < Lq){
    #pragma unroll
    for (int ii=0; ii<9; ii++) R[k*9+ii] = (ii==0||ii==4||ii==8) ? 1.f : 0.f;
    t[k*3] = 0.f; t[k*3+1] = 0.f; t[k*3+2] = 0.f;
  }
}

// ------------- pack [K,N] fp32 weight into MFMA-B hi/lo bf16 layout -------------
__global__ __launch_bounds__(256) void k_pack(
    const float* __restrict__ W, int K, int N, __hip_bfloat16* __restrict__ out){
  int idx = blockIdx.x*256 + threadIdx.x;
  if (idx >= K*N) return;
  int j = idx & 7, lane = (idx>>3) & 63, rest = idx >> 9;
  int nt = N >> 4;
  int tn = rest % nt, tk = rest / nt;
  int k = tk*32 + (lane>>4)*8 + j;
  int n = tn*16 + (lane&15);
  float v = W[(size_t)k*N + n];
  short h = f2bf(v);
  short l = f2bf(v - bf2f(h));
  size_t base = (size_t)rest*1024 + (idx & 511);
  out[base]       = s2b(h);
  out[base + 512] = s2b(l);
}

// ------------- pack concatenated projection weight (virtual [256,1152]) -------------
__global__ __launch_bounds__(256) void k_pack_cat(
    const float* __restrict__ wq, const float* __restrict__ wk, const float* __restrict__ wv,
    const float* __restrict__ wqp, const float* __restrict__ wkp, const float* __restrict__ wvp,
    __hip_bfloat16* __restrict__ out){
  int idx = blockIdx.x*256 + threadIdx.x;
  if (idx >= CSd*NPROJ) return;
  int j = idx & 7, lane = (idx>>3) & 63, rest = idx >> 9;
  const int nt = NPROJ >> 4;
  int tn = rest % nt, tk = rest / nt;
  int k = tk*32 + (lane>>4)*8 + j;
  int n = tn*16 + (lane&15);
  float v;
  if      (n < 256) v = wq[k*256 + n];
  else if (n < 512) v = wk[k*256 + n-256];
  else if (n < 768) v = wv[k*256 + n-512];
  else if (n < 864) v = wqp[k*96 + n-768];
  else if (n < 960) v = wkp[k*96 + n-864];
  else              v = wvp[k*192 + n-960];
  short h = f2bf(v);
  short l = f2bf(v - bf2f(h));
  size_t base = (size_t)rest*1024 + (idx & 511);
  out[base]       = s2b(h);
  out[base + 512] = s2b(l);
}

// ------------- split-precision MFMA GEMM (fp32 A); NST = 16-col tiles per block ----
template<int NST>
__global__ __launch_bounds__(256) void k_gemm_mfma(
    const float* __restrict__ A, int K,
    const __hip_bfloat16* __restrict__ Bp, int N,
    const float* __restrict__ bias,
    float* __restrict__ Cf,
    int relu, const float* __restrict__ rowscale){
  int tid = threadIdx.x;
  int wave = tid>>6, lane = tid&63;
  int i0 = blockIdx.y*64 + wave*16;
  int n0 = blockIdx.x*(NST*16);
  int quad = lane>>4, l16 = lane&15;
  floatx4 acc[NST] = {};
  const int ntiles = N >> 4;
  const float* arow = A + (size_t)(i0 + l16)*K + quad*8;
  const __hip_bfloat16* bbase = Bp + ((size_t)(n0>>4))*1024 + (size_t)(lane&63)*8;
  for (int k0=0; k0<K; k0+=32){
    float4 v0 = *(const float4*)(arow + k0);
    float4 v1 = *(const float4*)(arow + k0 + 4);
    float av[8] = {v0.x,v0.y,v0.z,v0.w,v1.x,v1.y,v1.z,v1.w};
    shortx8 ahi, alo;
    #pragma unroll
    for (int j=0; j<8; j++){
      short h = f2bf(av[j]);
      ahi[j] = h;
      alo[j] = f2bf(av[j] - bf2f(h));
    }
    const __hip_bfloat16* bt = bbase + (size_t)(k0>>5)*ntiles*1024;
    #pragma unroll
    for (int s=0; s<NST; s++){
      shortx8 bhi = *(const shortx8*)(bt + s*1024);
      shortx8 blo = *(const shortx8*)(bt + s*1024 + 512);
      acc[s] = __builtin_amdgcn_mfma_f32_16x16x32_bf16(ahi, bhi, acc[s], 0, 0, 0);
      acc[s] = __builtin_amdgcn_mfma_f32_16x16x32_bf16(alo, bhi, acc[s], 0, 0, 0);
      acc[s] = __builtin_amdgcn_mfma_f32_16x16x32_bf16(ahi, blo, acc[s], 0, 0, 0);
    }
  }
  #pragma unroll
  for (int s=0; s<NST; s++){
    int n = n0 + s*16 + l16;
    float bs = bias ? bias[n] : 0.f;
    #pragma unroll
    for (int r=0; r<4; r++){
      int m = i0 + quad*4 + r;
      float v = acc[s][r] + bs;
      if (relu) v = fmaxf(v, 0.f);
      if (rowscale) v *= rowscale[m];
      Cf[(size_t)m*N + n] = v;
    }
  }
}

// ------------- convert sc (fp32) -> scA16 MFMA-A hi/lo fragments -------------
__global__ __launch_bounds__(256) void k_cvtA(
    const float* __restrict__ sc, short* __restrict__ scA16){
  int idx = blockIdx.x*256 + threadIdx.x;   // 16384 = 512*32
  int i = idx>>5, c5 = idx&31;
  int c0 = c5*8, kc = c5>>2, quad = c5&3;
  float4 v0 = *(const float4*)(sc + (size_t)i*CSd + c0);
  float4 v1 = *(const float4*)(sc + (size_t)i*CSd + c0 + 4);
  float av[8] = {v0.x,v0.y,v0.z,v0.w,v1.x,v1.y,v1.z,v1.w};
  shortx8 hi, lo;
  #pragma unroll
  for (int j=0; j<8; j++){
    short h = f2bf(av[j]);
    hi[j] = h; lo[j] = f2bf(av[j] - bf2f(h));
  }
  size_t off = ((size_t)(kc*512 + i)*4 + quad)*8;
  *(shortx8*)(scA16 + off)          = hi;
  *(shortx8*)(scA16 + off + 131072) = lo;
}

// ------------- proj GEMM reading pre-packed A fragments; 16-col tiles, 576 blocks ---
__global__ __launch_bounds__(256) void k_gemm_proj(
    const short* __restrict__ scA16,
    const __hip_bfloat16* __restrict__ Bp,
    const float* __restrict__ bias,
    float* __restrict__ Cf){
  int tid = threadIdx.x;
  int wave = tid>>6, lane = tid&63;
  int i0 = blockIdx.y*64 + wave*16;
  int n0 = blockIdx.x*16;
  int quad = lane>>4, l16 = lane&15;
  floatx4 acc = {};
  const short* abase = scA16 + ((size_t)(i0 + l16)*4 + quad)*8;
  const __hip_bfloat16* bbase = Bp + (size_t)blockIdx.x*1024 + (size_t)lane*8;
  #pragma unroll
  for (int kc=0; kc<8; kc++){
    shortx8 ahi = *(const shortx8*)(abase + kc*16384);
    shortx8 alo = *(const shortx8*)(abase + kc*16384 + 131072);
    const __hip_bfloat16* bt = bbase + (size_t)kc*72*1024;
    shortx8 bhi = *(const shortx8*)bt;
    shortx8 blo = *(const shortx8*)(bt + 512);
    acc = __builtin_amdgcn_mfma_f32_16x16x32_bf16(ahi, bhi, acc, 0, 0, 0);
    acc = __builtin_amdgcn_mfma_f32_16x16x32_bf16(alo, bhi, acc, 0, 0, 0);
    acc = __builtin_amdgcn_mfma_f32_16x16x32_bf16(ahi, blo, acc, 0, 0, 0);
  }
  int n = n0 + l16;
  float bs = bias[n];
  #pragma unroll
  for (int r=0; r<4; r++)
    Cf[(size_t)(i0 + quad*4 + r)*NPROJ + n] = acc[r] + bs;
}

// ------------- ipa GEMM from cat fragments: split-K x4, 512 blocks ----------------
// C = 4 planes of 512x256 at C + ks*131072; bias added on plane 0 only.
__global__ __launch_bounds__(256) void k_gemm_ipa(
    const short* __restrict__ catA16, const __hip_bfloat16* __restrict__ Bp,
    const float* __restrict__ bias, float* __restrict__ C){
  int tid = threadIdx.x;
  int wave = tid>>6, lane = tid&63;
  int ks = blockIdx.y >> 3;               // 0..3
  int i0 = (blockIdx.y & 7)*64 + wave*16;
  int n0 = blockIdx.x*16;
  int quad = lane>>4, l16 = lane&15;
  floatx4 acc = {};
  const short* abase = catA16 + (size_t)(ks*12)*16384 + (size_t)(i0 + l16)*32 + quad*8;
  const __hip_bfloat16* bbase = Bp + ((size_t)(ks*12*16 + blockIdx.x))*1024 + (size_t)lane*8;
  #pragma unroll
  for (int kc=0; kc<12; kc++){
    shortx8 ahi = *(const shortx8*)(abase + kc*16384);
    shortx8 alo = *(const shortx8*)(abase + kc*16384 + CAT_LO);
    const __hip_bfloat16* bt = bbase + (size_t)kc*16*1024;
    shortx8 bhi = *(const shortx8*)bt;
    shortx8 blo = *(const shortx8*)(bt + 512);
    acc = __builtin_amdgcn_mfma_f32_16x16x32_bf16(ahi, bhi, acc, 0, 0, 0);
    acc = __builtin_amdgcn_mfma_f32_16x16x32_bf16(alo, bhi, acc, 0, 0, 0);
    acc = __builtin_amdgcn_mfma_f32_16x16x32_bf16(ahi, blo, acc, 0, 0, 0);
  }
  float* Cp = C + (size_t)ks*131072;
  int n = n0 + l16;
  float bs = ks ? 0.f : bias[n];
  #pragma unroll
  for (int r=0; r<4; r++)
    Cp[(size_t)(i0 + quad*4 + r)*CSd + n] = acc[r] + bs;
}

// ------------- LN over CS=256 row -------------
__global__ __launch_bounds__(256) void k_addln(
    const float* __restrict__ x, const float* __restrict__ y,
    const float* __restrict__ g, const float* __restrict__ b,
    float* __restrict__ out){
  __shared__ float red[4];
  int row = blockIdx.x, tid = threadIdx.x;
  float v = x[row*CSd + tid];
  if (y) v += y[row*CSd + tid];
  int wid = tid>>6, lane = tid&63;
  float s = wave_sum(v);
  if (lane==0) red[wid] = s;
  __syncthreads();
  float mu = (red[0]+red[1]+red[2]+red[3]) * (1.f/CSd);
  __syncthreads();
  float d = v - mu;
  float s2 = wave_sum(d*d);
  if (lane==0) red[wid] = s2;
  __syncthreads();
  float var = (red[0]+red[1]+red[2]+red[3]) * (1.f/CSd);
  float rs = rsqrtf(var + 1e-5f);
  out[row*CSd + tid] = d*rs*g[tid] + b[tid];
}

// ------------- zn LN: pair_bias (half) + znt bf16 [i][c][j] -------------
// LDS diet: wpb/g/b read directly from global (L1-resident); LDS used ONLY for
// the Zt transpose. ~32 LDS ops/thread vs ~106 before.
__global__ __launch_bounds__(1024, 4) void k_lnz_pb(
    const float* __restrict__ z, const float* __restrict__ g, const float* __restrict__ b,
    const float* __restrict__ wpb, __half* __restrict__ pb, __hip_bfloat16* __restrict__ znt){
  __shared__ float Zt[64*129];       // 33024 B
  int tid = threadIdx.x;
  size_t row0 = (size_t)blockIdx.x*64;
  int ib = (int)(row0 >> 9), j0 = (int)(row0 & 511);
  // phase 1: each wave loads one row (512B) per iter as float2
  {
    int w = tid>>6, lane = tid&63;
    #pragma unroll
    for (int it=0; it<4; it++){
      int row = it*16 + w;
      const float2 v = *(const float2*)(z + (row0+row)*(size_t)CZd + lane*2);
      Zt[row*129 + lane*2]     = v.x;
      Zt[row*129 + lane*2 + 1] = v.y;
    }
  }
  __syncthreads();
  // phase 2: stats + in-place normalize + pb (register-resident; wpb/g/b from L1)
  {
    int r = tid>>4, q = tid&15;
    int rot = 2*(q>>2);
    float S1=0.f, S2=0.f;
    float zv[8];
    #pragma unroll
    for (int i=0; i<8; i++){
      int ii = (i + rot) & 7;
      float v = Zt[r*129 + q*8 + ii];
      zv[i] = v;
      S1 += v; S2 += v*v;
    }
    S1 += __shfl_xor(S1,1); S2 += __shfl_xor(S2,1);
    S1 += __shfl_xor(S1,2); S2 += __shfl_xor(S2,2);
    S1 += __shfl_xor(S1,4); S2 += __shfl_xor(S2,4);
    S1 += __shfl_xor(S1,8); S2 += __shfl_xor(S2,8);
    float mu = S1 * (1.f/128.f);
    float var = S2 * (1.f/128.f) - mu*mu;
    float rs = rsqrtf(var + 1e-5f);
    float d[8] = {};
    #pragma unroll
    for (int i=0; i<8; i++){
      int ii = (i + rot) & 7;
      int c = q*8 + ii;
      float znv = (zv[i]-mu)*rs*g[c] + b[c];
      Zt[r*129 + c] = znv;
      const float4 w0 = *(const float4*)(wpb + c*8);
      const float4 w1 = *(const float4*)(wpb + c*8 + 4);
      d[0] += znv*w0.x; d[1] += znv*w0.y; d[2] += znv*w0.z; d[3] += znv*w0.w;
      d[4] += znv*w1.x; d[5] += znv*w1.y; d[6] += znv*w1.z; d[7] += znv*w1.w;
    }
    #pragma unroll
    for (int h=0; h<8; h++){
      d[h] += __shfl_xor(d[h],1);
      d[h] += __shfl_xor(d[h],2);
      d[h] += __shfl_xor(d[h],4);
      d[h] += __shfl_xor(d[h],8);
    }
    if (q == 0){
      #pragma unroll
      for (int h=0; h<8; h++)
        pb[((size_t)(h*Lq + ib))*Lq + j0 + r] = __float2half(d[h]);
    }
  }
  __syncthreads();
  // phase 3: repack; thread (c = tid>>3, jg = tid&7) packs 8 j -> one dwordx4 store
  {
    int c = tid>>3, jg = tid&7;
    int jb = jg*8;
    unsigned int o[4];
    #pragma unroll
    for (int k=0; k<4; k++){
      float z0 = Zt[(jb+2*k)*129 + c];
      float z1 = Zt[(jb+2*k+1)*129 + c];
      o[k] = ((unsigned int)(unsigned short)f2bf(z0)) |
             (((unsigned int)(unsigned short)f2bf(z1)) << 16);
    }
    unsigned short* zo = (unsigned short*)znt;
    uint4 pk = make_uint4(o[0],o[1],o[2],o[3]);
    *(uint4*)(zo + ((size_t)(ib*128 + c))*512 + j0 + jb) = pk;
  }
}

// ------------- pack Q'/K'/V' in MFMA layouts (vectorized), compute qn/kn -------------
__global__ __launch_bounds__(256) void k_packqkv(
    const float* __restrict__ P, const float* __restrict__ R, const float* __restrict__ t,
    const float* __restrict__ gamma, int zfill,
    float* __restrict__ Qp, __hip_bfloat16* __restrict__ Kp, __hip_bfloat16* __restrict__ Vp,
    float* __restrict__ qn, float* __restrict__ kn){
  int idx = blockIdx.x*256 + threadIdx.x;   // 3*32768
  int region = idx >> 15;
  int rem = idx & 32767;
  if (region == 0){
    int oct = rem & 7, h = (rem>>3)&7, j = rem>>6;
    float v[8] = {0.f,0.f,0.f,0.f,0.f,0.f,0.f,0.f};
    const float* Prow = P + (size_t)j*NPROJ;
    if (oct < 4){
      float4 a = *(const float4*)(Prow + 256 + h*CHd + oct*8);
      float4 b4 = *(const float4*)(Prow + 256 + h*CHd + oct*8 + 4);
      v[0]=a.x; v[1]=a.y; v[2]=a.z; v[3]=a.w; v[4]=b4.x; v[5]=b4.y; v[6]=b4.z; v[7]=b4.w;
    } else if (oct < 6){
      const float* kp = Prow + 864 + h*12;
      float4 k0 = *(const float4*)kp;
      float4 k1 = *(const float4*)(kp+4);
      float4 k2 = *(const float4*)(kp+8);
      float kv[12] = {k0.x,k0.y,k0.z,k0.w,k1.x,k1.y,k1.z,k1.w,k2.x,k2.y,k2.z,k2.w};
      float Rl[9];
      #pragma unroll
      for (int ii=0; ii<9; ii++) Rl[ii] = R[j*9+ii];
      float tv[3] = {t[j*3], t[j*3+1], t[j*3+2]};
      float gvals[12];
      #pragma unroll
      for (int p=0; p<4; p++)
        #pragma unroll
        for (int ax=0; ax<3; ax++)
          gvals[p*3+ax] = Rl[ax*3]*kv[p*3] + Rl[ax*3+1]*kv[p*3+1] + Rl[ax*3+2]*kv[p*3+2] + tv[ax];
      if (oct == 4){
        #pragma unroll
        for (int m=0; m<8; m++) v[m] = gvals[m];
      } else {
        #pragma unroll
        for (int m=0; m<4; m++) v[m] = gvals[8+m];
        float acc = 0.f;
        #pragma unroll
        for (int m=0; m<12; m++) acc += gvals[m]*gvals[m];
        kn[j*Hd + h] = acc;
      }
    } else {
      if (!zfill) return;
    }
    shortx8 hi, lo;
    #pragma unroll
    for (int m=0; m<8; m++){
      short hh = f2bf(v[m]);
      hi[m] = hh; lo[m] = f2bf(v[m] - bf2f(hh));
    }
    int kc = oct>>2, jt = j>>4, l16 = j&15, quad = oct&3;
    size_t base = (size_t)((h*2+kc)*32 + jt)*1024 + (quad*16+l16)*8;
    short* kp16 = (short*)Kp;
    *(shortx8*)(kp16 + base)       = hi;
    *(shortx8*)(kp16 + base + 512) = lo;
  } else if (region == 1){
    int n = rem & 63, h = (rem>>6)&7, jg = rem>>9;
    int jb = jg*8;
    float v[8] = {0.f,0.f,0.f,0.f,0.f,0.f,0.f,0.f};
    if (n < 32){
      #pragma unroll
      for (int m=0; m<8; m++) v[m] = P[(size_t)(jb+m)*NPROJ + 512 + h*CHd + n];
    } else if (n < 56){
      int p = (n-32)/3, ax = (n-32)%3;
      #pragma unroll
      for (int m=0; m<8; m++){
        int j = jb+m;
        const float* vp = P + (size_t)j*NPROJ + 960 + h*24 + p*3;
        const float* Rr = R + j*9 + ax*3;
        v[m] = Rr[0]*vp[0] + Rr[1]*vp[1] + Rr[2]*vp[2] + t[j*3+ax];
      }
    } else {
      if (!zfill) return;
    }
    shortx8 hi, lo;
    #pragma unroll
    for (int m=0; m<8; m++){
      short hh = f2bf(v[m]);
      hi[m] = hh; lo[m] = f2bf(v[m] - bf2f(hh));
    }
    int kc2 = jg>>2, w = n>>4, l16 = n&15, quad = jg&3;
    size_t base = (size_t)((h*16+kc2)*4 + w)*1024 + (quad*16+l16)*8;
    short* vp16 = (short*)Vp;
    *(shortx8*)(vp16 + base)       = hi;
    *(shortx8*)(vp16 + base + 512) = lo;
  } else {
    int oct = rem & 7, h = (rem>>3)&7, i = rem>>6;
    float v[8] = {0.f,0.f,0.f,0.f,0.f,0.f,0.f,0.f};
    const float* Prow = P + (size_t)i*NPROJ;
    if (oct < 4){
      float4 a = *(const float4*)(Prow + h*CHd + oct*8);
      float4 b4 = *(const float4*)(Prow + h*CHd + oct*8 + 4);
      const float sc = WLC*ISC;
      v[0]=a.x*sc; v[1]=a.y*sc; v[2]=a.z*sc; v[3]=a.w*sc;
      v[4]=b4.x*sc; v[5]=b4.y*sc; v[6]=b4.z*sc; v[7]=b4.w*sc;
    } else if (oct < 6){
      const float* qp = Prow + 768 + h*12;
      float4 k0 = *(const float4*)qp;
      float4 k1 = *(const float4*)(qp+4);
      float4 k2 = *(const float4*)(qp+8);
      float kv[12] = {k0.x,k0.y,k0.z,k0.w,k1.x,k1.y,k1.z,k1.w,k2.x,k2.y,k2.z,k2.w};
      float Rl[9];
      #pragma unroll
      for (int ii=0; ii<9; ii++) Rl[ii] = R[i*9+ii];
      float tv[3] = {t[i*3], t[i*3+1], t[i*3+2]};
      float gvals[12];
      #pragma unroll
      for (int p=0; p<4; p++)
        #pragma unroll
        for (int ax=0; ax<3; ax++)
          gvals[p*3+ax] = Rl[ax*3]*kv[p*3] + Rl[ax*3+1]*kv[p*3+1] + Rl[ax*3+2]*kv[p*3+2] + tv[ax];
      float sc = WLC*WCC*gamma[h];
      if (oct == 4){
        #pragma unroll
        for (int m=0; m<8; m++) v[m] = gvals[m]*sc;
      } else {
        #pragma unroll
        for (int m=0; m<4; m++) v[m] = gvals[8+m]*sc;
        float acc = 0.f;
        #pragma unroll
        for (int m=0; m<12; m++) acc += gvals[m]*gvals[m];
        qn[i*Hd + h] = acc;
      }
    } else {
      if (!zfill) return;
    }
    float* qrow = Qp + ((size_t)h*512 + i)*64 + oct*8;
    *(float4*)qrow       = make_float4(v[0],v[1],v[2],v[3]);
    *(float4*)(qrow + 4) = make_float4(v[4],v[5],v[6],v[7]);
  }
}

// ------------- fused attention: 16 q-rows/block, 1024 threads (16 waves) -------------
__global__ __launch_bounds__(1024) void k_attn(
    const float* __restrict__ Qp, const __hip_bfloat16* __restrict__ Kp,
    const __hip_bfloat16* __restrict__ Vp,
    const float* __restrict__ qn, const float* __restrict__ kn,
    const __half* __restrict__ pb, const float* __restrict__ maskb,
    const float* __restrict__ gamma,
    const float* __restrict__ R, const float* __restrict__ t,
    __hip_bfloat16* __restrict__ a16hi,
    short* __restrict__ catA16){
  __shared__ float At[16][516];
  __shared__ short AbfH[16*4*16*8];   // [kc][quad][row][jj]
  __shared__ short AbfL[16*4*16*8];
  __shared__ float Pv[3][16][68];
  __shared__ float Ot[16][36];
  __shared__ float qnL[16];
  int tid = threadIdx.x;
  int i0 = blockIdx.x*16, h = blockIdx.y;
  int wave = tid>>6, lane = tid&63, quad = lane>>4, l16 = lane&15;
  int kg = wave>>2, ng = wave&3;
  float gam = gamma[h];
  float coef = 0.5f*WLC*WCC*gam;
  if (tid < 16) qnL[tid] = qn[(i0+tid)*Hd + h];
  __syncthreads();
  // Q fragments (16 real rows)
  const float* qrow = Qp + ((size_t)h*512 + i0 + l16)*64 + quad*8;
  shortx8 qhi[2], qlo[2];
  #pragma unroll
  for (int kc=0; kc<2; kc++){
    float4 v0 = *(const float4*)(qrow + kc*32);
    float4 v1 = *(const float4*)(qrow + kc*32 + 4);
    float av[8] = {v0.x,v0.y,v0.z,v0.w,v1.x,v1.y,v1.z,v1.w};
    #pragma unroll
    for (int j=0; j<8; j++){
      short hh = f2bf(av[j]);
      qhi[kc][j] = hh; qlo[kc][j] = f2bf(av[j] - bf2f(hh));
    }
  }
  // QK^T: 32 j-tiles over 16 waves, 2 iters
  #pragma unroll
  for (int it=0; it<2; it++){
    int jt = it*16 + wave;
    floatx4 acc = {};
    #pragma unroll
    for (int kc=0; kc<2; kc++){
      const __hip_bfloat16* bt = Kp + (size_t)((h*2+kc)*32 + jt)*1024 + lane*8;
      shortx8 bhi = *(const shortx8*)bt;
      shortx8 blo = *(const shortx8*)(bt + 512);
      acc = __builtin_amdgcn_mfma_f32_16x16x32_bf16(qhi[kc], bhi, acc, 0, 0, 0);
      acc = __builtin_amdgcn_mfma_f32_16x16x32_bf16(qlo[kc], bhi, acc, 0, 0, 0);
      acc = __builtin_amdgcn_mfma_f32_16x16x32_bf16(qhi[kc], blo, acc, 0, 0, 0);
    }
    int j = jt*16 + l16;
    float knj = kn[j*Hd + h];
    float mbj = maskb[j];
    #pragma unroll
    for (int r=0; r<4; r++){
      int i = quad*4 + r;
      float pbv = __half2float(pb[((size_t)(h*Lq) + i0 + i)*Lq + j]);
      At[i][j] = acc[r] + WLC*pbv + mbj - coef*(qnL[i] + knj);
    }
  }
  __syncthreads();
  // softmax: wave w owns row w (16 waves, 16 rows); shuffle-only reductions
  {
    int w = wave;
    float v[8];
    float m = -1e30f;
    #pragma unroll
    for (int k=0; k<8; k++){ v[k] = At[w][lane + 64*k]; m = fmaxf(m, v[k]); }
    #pragma unroll
    for (int msk=32; msk; msk>>=1) m = fmaxf(m, __shfl_xor(m, msk));
    float ssum = 0.f;
    #pragma unroll
    for (int k=0; k<8; k++){ float e = __expf(v[k]-m); v[k]=e; ssum += e; }
    #pragma unroll
    for (int msk=32; msk; msk>>=1) ssum += __shfl_xor(ssum, msk);
    float inv = 1.f/ssum;
    #pragma unroll
    for (int k=0; k<8; k++){
      int cc = lane + 64*k;
      float p = v[k]*inv;
      short hh = f2bf(p);
      short ll = f2bf(p - bf2f(hh));
      a16hi[(((size_t)(i0+w)*16 + (cc>>5))*8 + h)*32 + (cc&31)] = s2b(hh);
      int off = ((((cc>>5)*4 + ((cc>>3)&3))*16 + w)<<3) + (cc&7);
      AbfH[off] = hh;
      AbfL[off] = ll;
    }
  }
  __syncthreads();
  // AV: wave (kg, ng): 4 kc each, n-tile ng; 3 partial groups reduce via LDS
  floatx4 acc2 = {};
  #pragma unroll
  for (int kk=0; kk<4; kk++){
    int kc2 = kg*4 + kk;
    int aoff = (((kc2*4 + quad)*16 + l16))<<3;
    shortx8 ahi = *(const shortx8*)&AbfH[aoff];
    shortx8 alo = *(const shortx8*)&AbfL[aoff];
    const __hip_bfloat16* bt = Vp + (size_t)((h*16+kc2)*4 + ng)*1024 + lane*8;
    shortx8 bhi = *(const shortx8*)bt;
    shortx8 blo = *(const shortx8*)(bt + 512);
    acc2 = __builtin_amdgcn_mfma_f32_16x16x32_bf16(ahi, bhi, acc2, 0, 0, 0);
    acc2 = __builtin_amdgcn_mfma_f32_16x16x32_bf16(alo, bhi, acc2, 0, 0, 0);
    acc2 = __builtin_amdgcn_mfma_f32_16x16x32_bf16(ahi, blo, acc2, 0, 0, 0);
  }
  if (kg > 0){
    #pragma unroll
    for (int r=0;r<4;r++) Pv[kg-1][quad*4+r][ng*16+l16] = acc2[r];
  }
  __syncthreads();
  if (kg == 0){
    int n = ng*16 + l16;
    #pragma unroll
    for (int r=0;r<4;r++){
      int i = quad*4+r;
      float v = acc2[r] + Pv[0][i][n] + Pv[1][i][n] + Pv[2][i][n];
      if (n < 32) cat_store(catA16, h*CHd + n, i0+i, v);
      else        Ot[i][n-32] = v;
    }
  }
  __syncthreads();
  if (tid < 128){
    int i = tid>>3, p = tid&7, gi = i0+i;
    float o0 = Ot[i][p*3], o1 = Ot[i][p*3+1], o2 = Ot[i][p*3+2];
    float d0 = o0 - t[gi*3], d1 = o1 - t[gi*3+1], d2 = o2 - t[gi*3+2];
    const float* Rm = R + gi*9;
    float l0 = Rm[0]*d0 + Rm[3]*d1 + Rm[6]*d2;
    float l1 = Rm[1]*d0 + Rm[4]*d1 + Rm[7]*d2;
    float l2 = Rm[2]*d0 + Rm[5]*d1 + Rm[8]*d2;
    int kb = 256 + h*24 + p*3;
    cat_store(catA16, kb,   gi, l0);
    cat_store(catA16, kb+1, gi, l1);
    cat_store(catA16, kb+2, gi, l2);
    cat_store(catA16, 448 + h*8 + p, gi, sqrtf(l0*l0 + l1*l1 + l2*l2 + 1e-8f));
  }
}

// ------------- opair = a @ zn via MFMA (a hi-only), 512 threads -------------
__global__ __launch_bounds__(512) void k_opair_mfma(
    const __hip_bfloat16* __restrict__ a16hi,
    const __hip_bfloat16* __restrict__ znt, short* __restrict__ catA16){
  int i = blockIdx.x;
  int tid = threadIdx.x;
  int wave = tid>>6, lane = tid&63, quad = lane>>4, l16 = lane&15;
  int nt = wave;
  floatx4 acc = {};
  const __hip_bfloat16* abase_h = a16hi + ((size_t)i*16*8 + (l16&7))*32 + quad*8;
  const __hip_bfloat16* zb = znt + ((size_t)i*128 + nt*16 + l16)*512 + quad*8;
  #pragma unroll
  for (int kt=0; kt<16; kt++){
    shortx8 ah = *(const shortx8*)(abase_h + kt*256);
    shortx8 b0 = *(const shortx8*)(zb + kt*32);
    acc = __builtin_amdgcn_mfma_f32_16x16x32_bf16(ah, b0, acc, 0, 0, 0);
  }
  if (quad < 2){
    #pragma unroll
    for (int r=0; r<4; r++){
      int h = quad*4 + r;
      cat_store(catA16, 512 + h*CZd + nt*16 + l16, i, acc[r]);
    }
  }
}

// ------------- mega: LN + 3 GEMMs + LN + upd + frame update (1024 threads) ---------
__device__ __forceinline__ void gemm_bf16w(
    const short* __restrict__ AHp, const short* __restrict__ ALp,
    short* __restrict__ OH, short* __restrict__ OL, float (*Yf)[260],
    const __hip_bfloat16* __restrict__ Wp, const float* __restrict__ bias,
    bool relu, int tid){
  int wave = tid>>6, lane = tid&63, quad = lane>>4, l16 = lane&15;
  floatx4 acc = {};
  #pragma unroll
  for (int kc=0; kc<8; kc++){
    int aoff = (((kc*4 + quad)*16 + l16))<<3;
    shortx8 ahi = *(const shortx8*)&AHp[aoff];
    shortx8 alo = *(const shortx8*)&ALp[aoff];
    const __hip_bfloat16* bt = Wp + (size_t)(kc*16 + wave)*1024 + lane*8;
    shortx8 bhi = *(const shortx8*)bt;
    shortx8 blo = *(const shortx8*)(bt + 512);
    acc = __builtin_amdgcn_mfma_f32_16x16x32_bf16(ahi, bhi, acc, 0, 0, 0);
    acc = __builtin_amdgcn_mfma_f32_16x16x32_bf16(alo, bhi, acc, 0, 0, 0);
    acc = __builtin_amdgcn_mfma_f32_16x16x32_bf16(ahi, blo, acc, 0, 0, 0);
  }
  int n = wave*16 + l16;
  float bs = bias[n];
  #pragma unroll
  for (int r=0;r<4;r++){
    float v = acc[r] + bs;
    if (relu) v = fmaxf(v, 0.f);
    int row = quad*4 + r;
    if (OH){
      short hh = f2bf(v);
      int off = ((((n>>5)*4 + ((n>>3)&3))*16 + row)<<3) + (n&7);
      OH[off] = hh;
      OL[off] = f2bf(v - bf2f(hh));
    } else {
      Yf[row][n] = v;
    }
  }
}

__global__ __launch_bounds__(1024) void k_mega(
    float* __restrict__ scb, const float* __restrict__ ipa,
    const float* __restrict__ gi_, const float* __restrict__ bi_,
    const __hip_bfloat16* __restrict__ W1, const float* __restrict__ c1,
    const __hip_bfloat16* __restrict__ W2, const float* __restrict__ c2,
    const __hip_bfloat16* __restrict__ W3, const float* __restrict__ c3,
    const float* __restrict__ gt_, const float* __restrict__ bt_,
    const float* __restrict__ mask,
    const float* __restrict__ wbb, const float* __restrict__ bbb,
    float* __restrict__ R, float* __restrict__ t, short* __restrict__ scA16){
  __shared__ float As[16][260], Bs[16][260];
  __shared__ short AH[2][4096], AL[2][4096];
  __shared__ float rA[16][33], rB[16][33];
  __shared__ float mv[16][2];
  __shared__ float u6p[16][6][2];
  int tid = threadIdx.x;
  int i0 = blockIdx.x*16;
  int r = (tid>>5)&15, c5 = tid&31, c0 = c5*8;
  float v[8];
  // stage 0: LN(sc + ipa0+ipa1+ipa2+ipa3)
  if (tid < 512){
    const float* sr = scb + (size_t)(i0+r)*CSd + c0;
    const float* p0 = ipa + (size_t)(i0+r)*CSd + c0;
    const float* p1 = p0 + 131072;
    const float* p2 = p0 + 262144;
    const float* p3 = p0 + 393216;
    float s1=0.f, s2=0.f;
    #pragma unroll
    for (int k2=0;k2<8;k2++){
      float x = sr[k2] + p0[k2] + p1[k2] + p2[k2] + p3[k2];
      v[k2]=x; s1+=x; s2+=x*x;
    }
    rA[r][c5]=s1; rB[r][c5]=s2;
  }
  __syncthreads();
  if (tid<16){
    float s1=0.f,s2=0.f;
    #pragma unroll
    for (int c=0;c<32;c++){ s1+=rA[tid][c]; s2+=rB[tid][c]; }
    float mu = s1*(1.f/CSd), var = s2*(1.f/CSd) - mu*mu;
    mv[tid][0]=mu; mv[tid][1]=rsqrtf(var+1e-5f);
  }
  __syncthreads();
  if (tid < 512){
    float mu=mv[r][0], rs=mv[r][1];
    #pragma unroll
    for (int k2=0;k2<8;k2++){
      int col = c0+k2;
      float o = (v[k2]-mu)*rs*gi_[col] + bi_[col];
      As[r][col] = o;
      short hh = f2bf(o);
      int off = ((((col>>5)*4 + ((col>>3)&3))*16 + r)<<3) + (col&7);
      AH[0][off] = hh;
      AL[0][off] = f2bf(o - bf2f(hh));
    }
  }
  __syncthreads();
  gemm_bf16w(AH[0], AL[0], AH[1], AL[1], nullptr, W1, c1, true, tid);
  __syncthreads();
  gemm_bf16w(AH[1], AL[1], AH[0], AL[0], nullptr, W2, c2, true, tid);
  __syncthreads();
  gemm_bf16w(AH[0], AL[0], nullptr, nullptr, Bs, W3, c3, false, tid);
  __syncthreads();
  // stage 4: LN(sc_new + tr3*mask)
  if (tid < 512){
    float mk = mask[i0+r];
    float s1=0.f, s2=0.f;
    #pragma unroll
    for (int k2=0;k2<8;k2++){ float x = As[r][c0+k2] + Bs[r][c0+k2]*mk; v[k2]=x; s1+=x; s2+=x*x; }
    rA[r][c5]=s1; rB[r][c5]=s2;
  }
  __syncthreads();
  if (tid<16){
    float s1=0.f,s2=0.f;
    #pragma unroll
    for (int c=0;c<32;c++){ s1+=rA[tid][c]; s2+=rB[tid][c]; }
    float mu = s1*(1.f/CSd), var = s2*(1.f/CSd) - mu*mu;
    mv[tid][0]=mu; mv[tid][1]=rsqrtf(var+1e-5f);
  }
  __syncthreads();
  if (tid < 512){
    float mu=mv[r][0], rs=mv[r][1];
    float* out = scb + (size_t)(i0+r)*CSd + c0;
    shortx8 hi, lo;
    #pragma unroll
    for (int k2=0;k2<8;k2++){
      int col = c0+k2;
      float o = (v[k2]-mu)*rs*gt_[col] + bt_[col];
      As[r][col] = o;
      out[k2] = o;
      short hh = f2bf(o);
      hi[k2] = hh; lo[k2] = f2bf(o - bf2f(hh));
    }
    size_t off = ((size_t)((c5>>2)*512 + i0 + r)*4 + (c5&3))*8;
    *(shortx8*)(scA16 + off)          = hi;
    *(shortx8*)(scA16 + off + 131072) = lo;
  }
  __syncthreads();
  // stage 5: upd (192-thread k-split) + quat update
  if (tid < 192){
    int rr = tid/12, o = (tid%12)>>1, half = tid&1;
    float acc = half ? 0.f : bbb[o];
    int kb = half*128;
    for (int k2=kb; k2<kb+128; k2++) acc += As[rr][k2]*wbb[k2*6+o];
    u6p[rr][o][half] = acc;
  }
  __syncthreads();
  if (tid < 16){
    int gidx = i0 + tid;
    float uu[6];
    #pragma unroll
    for (int o=0;o<6;o++) uu[o] = u6p[tid][o][0] + u6p[tid][o][1];
    float bq = uu[0], cq = uu[1], dq = uu[2];
    float norm = sqrtf(1.f + bq*bq + cq*cq + dq*dq);
    float a = 1.f/norm, b_ = bq/norm, c_ = cq/norm, d_ = dq/norm;
    float dR[9];
    dR[0] = a*a + b_*b_ - c_*c_ - d_*d_; dR[1] = 2.f*(b_*c_ - a*d_); dR[2] = 2.f*(b_*d_ + a*c_);
    dR[3] = 2.f*(b_*c_ + a*d_); dR[4] = a*a - b_*b_ + c_*c_ - d_*d_; dR[5] = 2.f*(c_*d_ - a*b_);
    dR[6] = 2.f*(b_*d_ - a*c_); dR[7] = 2.f*(c_*d_ + a*b_); dR[8] = a*a - b_*b_ - c_*c_ + d_*d_;
    float mk = mask[gidx];
    float dt0 = uu[3]*mk, dt1 = uu[4]*mk, dt2 = uu[5]*mk;
    float Rm[9];
    #pragma unroll
    for (int ii=0; ii<9; ii++) Rm[ii] = R[gidx*9+ii];
    t[gidx*3]   += Rm[0]*dt0 + Rm[1]*dt1 + Rm[2]*dt2;
    t[gidx*3+1] += Rm[3]*dt0 + Rm[4]*dt1 + Rm[5]*dt2;
    t[gidx*3+2] += Rm[6]*dt0 + Rm[7]*dt1 + Rm[8]*dt2;
    #pragma unroll
    for (int ii=0; ii<3; ii++)
      #pragma unroll
      for (int jj=0; jj<3; jj++)
        R[gidx*9 + ii*3 + jj] = Rm[ii*3]*dR[jj] + Rm[ii*3+1]*dR[3+jj] + Rm[ii*3+2]*dR[6+jj];
  }
}

// ------------- final output write -------------
__global__ __launch_bounds__(256) void k_writeout(
    const float* __restrict__ sc, const float* __restrict__ R, const float* __restrict__ t,
    float* __restrict__ out){
  int idx = blockIdx.x*256 + threadIdx.x;
  if      (idx < 131072) out[idx] = sc[idx];
  else if (idx < 135680) out[idx] = R[idx-131072];
  else if (idx < 137216) out[idx] = t[idx-135680];
}

extern "C" void kernel_launch(void* const* d_in, const int* in_sizes, int n_in,
                              void* d_out, int out_size, void* d_ws, size_t ws_size,
                              hipStream_t stream){
  const float* s      = (const float*)d_in[0];
  const float* z      = (const float*)d_in[1];
  const float* mask   = (const float*)d_in[2];
  const float* ln_s_g = (const float*)d_in[3];
  const float* ln_s_b = (const float*)d_in[4];
  const float* ln_z_g = (const float*)d_in[5];
  const float* ln_z_b = (const float*)d_in[6];
  const float* w_init = (const float*)d_in[7];
  const float* b_init = (const float*)d_in[8];
  const float* ln_ipa_g = (const float*)d_in[9];
  const float* ln_ipa_b = (const float*)d_in[10];
  const float* ln_tr_g  = (const float*)d_in[11];
  const float* ln_tr_b  = (const float*)d_in[12];
  const float* wq = (const float*)d_in[13]; const float* bq = (const float*)d_in[14];
  const float* wk = (const float*)d_in[15]; const float* bk = (const float*)d_in[16];
  const float* wv = (const float*)d_in[17]; const float* bv = (const float*)d_in[18];
  const float* wqp = (const float*)d_in[19]; const float* bqp = (const float*)d_in[20];
  const float* wkp = (const float*)d_in[21]; const float* bkp = (const float*)d_in[22];
  const float* wvp = (const float*)d_in[23]; const float* bvp = (const float*)d_in[24];
  const float* wpb = (const float*)d_in[25];
  const float* head_w = (const float*)d_in[26];
  const float* wo = (const float*)d_in[27]; const float* bo = (const float*)d_in[28];
  const float* wt1 = (const float*)d_in[29]; const float* bt1 = (const float*)d_in[30];
  const float* wt2 = (const float*)d_in[31]; const float* bt2 = (const float*)d_in[32];
  const float* wt3 = (const float*)d_in[33]; const float* bt3 = (const float*)d_in[34];
  const float* wbb = (const float*)d_in[35]; const float* bbb = (const float*)d_in[36];

  float* W = (float*)d_ws;
  float* scb   = W + OFF_SC;
  __half*  pbb  = (__half*)(W + OFF_PB);
  float* Pb    = W + OFF_P;
  float* qnb   = W + OFF_QN;
  float* knb   = W + OFF_KN;
  __hip_bfloat16* a16hi = (__hip_bfloat16*)(W + OFF_A16);
  short* catA16 = (short*)(W + OFF_CAT);
  float* s0b   = W + OFF_S0;
  float* Rb    = W + OFF_R;
  float* tb    = W + OFF_T;
  float* gammab= W + OFF_GAMMA;
  float* maskb = W + OFF_MASKB;
  float* bcat  = W + OFF_BCAT;
  __hip_bfloat16* WinitP = (__hip_bfloat16*)(W + OFF_WINITP);
  __hip_bfloat16* Wt1P   = (__hip_bfloat16*)(W + OFF_WT1P);
  __hip_bfloat16* Wt2P   = (__hip_bfloat16*)(W + OFF_WT2P);
  __hip_bfloat16* Wt3P   = (__hip_bfloat16*)(W + OFF_WT3P);
  __hip_bfloat16* WoP    = (__hip_bfloat16*)(W + OFF_WOP);
  __hip_bfloat16* WcatP  = (__hip_bfloat16*)(W + OFF_WCATP);
  float* Qp = W + OFF_QP;
  __hip_bfloat16* Kp = (__hip_bfloat16*)(W + OFF_KP);
  __hip_bfloat16* Vp = (__hip_bfloat16*)(W + OFF_VP);
  short* scA16 = (short*)(W + OFF_SCA16);
  __hip_bfloat16* znt = (__hip_bfloat16*)(W + OFF_ZNT);

  k_setup<<<9, 256, 0, stream>>>(bq,bk,bv,bqp,bkp,bvp, head_w, mask, bcat, gammab, maskb, Rb, tb);
  k_pack_cat<<<CSd*NPROJ/256, 256, 0, stream>>>(wq,wk,wv,wqp,wkp,wvp, WcatP);
  k_pack<<<256,  256, 0, stream>>>(w_init, CSd, CSd, WinitP);
  k_pack<<<1536, 256, 0, stream>>>(wo, CATd, CSd, WoP);
  k_pack<<<256,  256, 0, stream>>>(wt1, CSd, CSd, Wt1P);
  k_pack<<<256,  256, 0, stream>>>(wt2, CSd, CSd, Wt2P);
  k_pack<<<256,  256, 0, stream>>>(wt3, CSd, CSd, Wt3P);

  k_addln<<<Lq, 256, 0, stream>>>(s, nullptr, ln_s_g, ln_s_b, s0b);
  k_gemm_mfma<4><<<dim3(4,8), 256, 0, stream>>>(s0b, CSd, WinitP, CSd, b_init, scb, 0, nullptr);
  k_cvtA<<<64, 256, 0, stream>>>(scb, scA16);
  k_lnz_pb<<<Lq*Lq/64, 1024, 0, stream>>>(z, ln_z_g, ln_z_b, wpb, pbb, znt);

  for (int it=0; it<8; ++it){
    k_gemm_proj<<<dim3(72,8), 256, 0, stream>>>(scA16, WcatP, bcat, Pb);
    k_packqkv<<<384, 256, 0, stream>>>(Pb, Rb, tb, gammab, (it==0)?1:0,
                                       Qp, Kp, Vp, qnb, knb);
    k_attn<<<dim3(32,8), 1024, 0, stream>>>(Qp, Kp, Vp, qnb, knb, pbb, maskb, gammab, Rb, tb,
                                            a16hi, catA16);
    k_opair_mfma<<<Lq, 512, 0, stream>>>(a16hi, znt, catA16);
    k_gemm_ipa<<<dim3(16,32), 256, 0, stream>>>(catA16, WoP, bo, Pb);
    k_mega<<<32, 1024, 0, stream>>>(scb, Pb, ln_ipa_g, ln_ipa_b,
                                    Wt1P, bt1, Wt2P, bt2, Wt3P, bt3,
                                    ln_tr_g, ln_tr_b, mask, wbb, bbb, Rb, tb, scA16);
  }
  k_writeout<<<536, 256, 0, stream>>>(scb, Rb, tb, (float*)d_out);
}

// Round 8
// 832.930 us; speedup vs baseline: 1.1021x; 1.1021x over previous
//
#include <hip/hip_runtime.h>
#include <hip/hip_bf16.h>
#include <hip/hip_fp16.h>
#include <math.h>

#define Lq 512
#define CSd 256
#define CZd 128
#define Hd 8
#define CHd 32
#define PQd 4
#define PVd 8
#define CATd 1536
#define NPROJ 1152

typedef __attribute__((ext_vector_type(4))) float floatx4;
typedef __attribute__((ext_vector_type(8))) short shortx8;

// ---------------- ws layout (float offsets) ----------------
#define OFF_SC      0         // 131072
#define OFF_PB      393216    // 1048576 (half)
#define OFF_P       1441792   // 589824  (P, then reused as 4 ipa planes 4*131072)
#define OFF_QN      2031616   // 4096
#define OFF_KN      2035712   // 4096
#define OFF_A16     2039808   // 2097152 (a16hi only)
#define OFF_CAT     4136960   // 786432 floats = catA16: hi plane 786432 shorts + lo plane
#define OFF_S0      4923392   // 131072
#define OFF_R       5054464   // 4608
#define OFF_T       5059072   // 1536
#define OFF_GAMMA   5060608   // 8
#define OFF_MASKB   5060616   // 512
#define OFF_BCAT    5061128   // 1152
#define OFF_WINITP  5062280   // 65536
#define OFF_WT1P    5127816   // 65536
#define OFF_WT2P    5193352   // 65536
#define OFF_WT3P    5258888   // 65536
#define OFF_WOP     5324424   // 393216
#define OFF_WCATP   5717640   // 294912
#define OFF_QP      6012552   // 262144 (fp32)
#define OFF_KP      6274696   // 262144 (=524288 bf16)
#define OFF_VP      6536840   // 262144 (=524288 bf16)
#define OFF_SCA16   6798984   // 131072 (=262144 shorts: hi plane 131072 + lo plane)
#define OFF_ZNT     6930056   // 16777216 (=33554432 bf16)  [i][c][j]

#define CAT_LO 786432

#define WLC 0.57735026918962576f
#define WCC 0.23570226039551584f
#define ISC 0.17677669529663687f

__device__ __forceinline__ float wave_sum(float v){
  #pragma unroll
  for (int m=32; m; m>>=1) v += __shfl_xor(v, m);
  return v;
}
__device__ __forceinline__ short f2bf(float v){
  __hip_bfloat16 h = (__hip_bfloat16)v;
  return __builtin_bit_cast(short, h);
}
__device__ __forceinline__ float bf2f(short s){
  unsigned u = ((unsigned)(unsigned short)s) << 16;
  return __builtin_bit_cast(float, u);
}
__device__ __forceinline__ __hip_bfloat16 s2b(short s){
  return __builtin_bit_cast(__hip_bfloat16, s);
}
// store one (row, col k) element of cat in MFMA-A hi/lo fragment layout
__device__ __forceinline__ void cat_store(short* __restrict__ catA16, int k, int row, float v){
  size_t off = (((size_t)(k>>5)*512 + row)*4 + ((k>>3)&3))*8 + (k&7);
  short hh = f2bf(v);
  catA16[off]          = hh;
  catA16[off + CAT_LO] = f2bf(v - bf2f(hh));
}

// ------------- setup -------------
__global__ __launch_bounds__(256) void k_setup(
    const float* __restrict__ bq, const float* __restrict__ bk, const float* __restrict__ bv,
    const float* __restrict__ bqp, const float* __restrict__ bkp, const float* __restrict__ bvp,
    const float* __restrict__ head_w, const float* __restrict__ mask,
    float* __restrict__ bcat, float* __restrict__ gamma,
    float* __restrict__ maskb, float* __restrict__ R, float* __restrict__ t){
  int k = blockIdx.x*256 + threadIdx.x;
  if (k < NPROJ){
    float v;
    if      (k < 256) v = bq[k];
    else if (k < 512) v = bk[k-256];
    else if (k < 768) v = bv[k-512];
    else if (k < 864) v = bqp[k-768];
    else if (k < 960) v = bkp[k-864];
    else              v = bvp[k-960];
    bcat[k] = v;
    return;
  }
  k -= NPROJ;
  if (k < Hd){ gamma[k] = log1pf(expf(head_w[k])); return; }
  k -= Hd;
  if (k < Lq){ maskb[k] = (mask[k] - 1.f)*1e9f; return; }
  k -= Lq;
  if (k < Lq){
    #pragma unroll
    for (int ii=0; ii<9; ii++) R[k*9+ii] = (ii==0||ii==4||ii==8) ? 1.f : 0.f;
    t[k*3] = 0.f; t[k*3+1] = 0.f; t[k*3+2] = 0.f;
  }
}

// ------------- pack [K,N] fp32 weight into MFMA-B hi/lo bf16 layout -------------
__global__ __launch_bounds__(256) void k_pack(
    const float* __restrict__ W, int K, int N, __hip_bfloat16* __restrict__ out){
  int idx = blockIdx.x*256 + threadIdx.x;
  if (idx >= K*N) return;
  int j = idx & 7, lane = (idx>>3) & 63, rest = idx >> 9;
  int nt = N >> 4;
  int tn = rest % nt, tk = rest / nt;
  int k = tk*32 + (lane>>4)*8 + j;
  int n = tn*16 + (lane&15);
  float v = W[(size_t)k*N + n];
  short h = f2bf(v);
  short l = f2bf(v - bf2f(h));
  size_t base = (size_t)rest*1024 + (idx & 511);
  out[base]       = s2b(h);
  out[base + 512] = s2b(l);
}

// ------------- pack concatenated projection weight (virtual [256,1152]) -------------
__global__ __launch_bounds__(256) void k_pack_cat(
    const float* __restrict__ wq, const float* __restrict__ wk, const float* __restrict__ wv,
    const float* __restrict__ wqp, const float* __restrict__ wkp, const float* __restrict__ wvp,
    __hip_bfloat16* __restrict__ out){
  int idx = blockIdx.x*256 + threadIdx.x;
  if (idx >= CSd*NPROJ) return;
  int j = idx & 7, lane = (idx>>3) & 63, rest = idx >> 9;
  const int nt = NPROJ >> 4;
  int tn = rest % nt, tk = rest / nt;
  int k = tk*32 + (lane>>4)*8 + j;
  int n = tn*16 + (lane&15);
  float v;
  if      (n < 256) v = wq[k*256 + n];
  else if (n < 512) v = wk[k*256 + n-256];
  else if (n < 768) v = wv[k*256 + n-512];
  else if (n < 864) v = wqp[k*96 + n-768];
  else if (n < 960) v = wkp[k*96 + n-864];
  else              v = wvp[k*192 + n-960];
  short h = f2bf(v);
  short l = f2bf(v - bf2f(h));
  size_t base = (size_t)rest*1024 + (idx & 511);
  out[base]       = s2b(h);
  out[base + 512] = s2b(l);
}

// ------------- split-precision MFMA GEMM (fp32 A); NST = 16-col tiles per block ----
template<int NST>
__global__ __launch_bounds__(256) void k_gemm_mfma(
    const float* __restrict__ A, int K,
    const __hip_bfloat16* __restrict__ Bp, int N,
    const float* __restrict__ bias,
    float* __restrict__ Cf,
    int relu, const float* __restrict__ rowscale){
  int tid = threadIdx.x;
  int wave = tid>>6, lane = tid&63;
  int i0 = blockIdx.y*64 + wave*16;
  int n0 = blockIdx.x*(NST*16);
  int quad = lane>>4, l16 = lane&15;
  floatx4 acc[NST] = {};
  const int ntiles = N >> 4;
  const float* arow = A + (size_t)(i0 + l16)*K + quad*8;
  const __hip_bfloat16* bbase = Bp + ((size_t)(n0>>4))*1024 + (size_t)(lane&63)*8;
  for (int k0=0; k0<K; k0+=32){
    float4 v0 = *(const float4*)(arow + k0);
    float4 v1 = *(const float4*)(arow + k0 + 4);
    float av[8] = {v0.x,v0.y,v0.z,v0.w,v1.x,v1.y,v1.z,v1.w};
    shortx8 ahi, alo;
    #pragma unroll
    for (int j=0; j<8; j++){
      short h = f2bf(av[j]);
      ahi[j] = h;
      alo[j] = f2bf(av[j] - bf2f(h));
    }
    const __hip_bfloat16* bt = bbase + (size_t)(k0>>5)*ntiles*1024;
    #pragma unroll
    for (int s=0; s<NST; s++){
      shortx8 bhi = *(const shortx8*)(bt + s*1024);
      shortx8 blo = *(const shortx8*)(bt + s*1024 + 512);
      acc[s] = __builtin_amdgcn_mfma_f32_16x16x32_bf16(ahi, bhi, acc[s], 0, 0, 0);
      acc[s] = __builtin_amdgcn_mfma_f32_16x16x32_bf16(alo, bhi, acc[s], 0, 0, 0);
      acc[s] = __builtin_amdgcn_mfma_f32_16x16x32_bf16(ahi, blo, acc[s], 0, 0, 0);
    }
  }
  #pragma unroll
  for (int s=0; s<NST; s++){
    int n = n0 + s*16 + l16;
    float bs = bias ? bias[n] : 0.f;
    #pragma unroll
    for (int r=0; r<4; r++){
      int m = i0 + quad*4 + r;
      float v = acc[s][r] + bs;
      if (relu) v = fmaxf(v, 0.f);
      if (rowscale) v *= rowscale[m];
      Cf[(size_t)m*N + n] = v;
    }
  }
}

// ------------- convert sc (fp32) -> scA16 MFMA-A hi/lo fragments -------------
__global__ __launch_bounds__(256) void k_cvtA(
    const float* __restrict__ sc, short* __restrict__ scA16){
  int idx = blockIdx.x*256 + threadIdx.x;   // 16384 = 512*32
  int i = idx>>5, c5 = idx&31;
  int c0 = c5*8, kc = c5>>2, quad = c5&3;
  float4 v0 = *(const float4*)(sc + (size_t)i*CSd + c0);
  float4 v1 = *(const float4*)(sc + (size_t)i*CSd + c0 + 4);
  float av[8] = {v0.x,v0.y,v0.z,v0.w,v1.x,v1.y,v1.z,v1.w};
  shortx8 hi, lo;
  #pragma unroll
  for (int j=0; j<8; j++){
    short h = f2bf(av[j]);
    hi[j] = h; lo[j] = f2bf(av[j] - bf2f(h));
  }
  size_t off = ((size_t)(kc*512 + i)*4 + quad)*8;
  *(shortx8*)(scA16 + off)          = hi;
  *(shortx8*)(scA16 + off + 131072) = lo;
}

// ------------- proj GEMM reading pre-packed A fragments; 16-col tiles, 576 blocks ---
__global__ __launch_bounds__(256) void k_gemm_proj(
    const short* __restrict__ scA16,
    const __hip_bfloat16* __restrict__ Bp,
    const float* __restrict__ bias,
    float* __restrict__ Cf){
  int tid = threadIdx.x;
  int wave = tid>>6, lane = tid&63;
  int i0 = blockIdx.y*64 + wave*16;
  int n0 = blockIdx.x*16;
  int quad = lane>>4, l16 = lane&15;
  floatx4 acc = {};
  const short* abase = scA16 + ((size_t)(i0 + l16)*4 + quad)*8;
  const __hip_bfloat16* bbase = Bp + (size_t)blockIdx.x*1024 + (size_t)lane*8;
  #pragma unroll
  for (int kc=0; kc<8; kc++){
    shortx8 ahi = *(const shortx8*)(abase + kc*16384);
    shortx8 alo = *(const shortx8*)(abase + kc*16384 + 131072);
    const __hip_bfloat16* bt = bbase + (size_t)kc*72*1024;
    shortx8 bhi = *(const shortx8*)bt;
    shortx8 blo = *(const shortx8*)(bt + 512);
    acc = __builtin_amdgcn_mfma_f32_16x16x32_bf16(ahi, bhi, acc, 0, 0, 0);
    acc = __builtin_amdgcn_mfma_f32_16x16x32_bf16(alo, bhi, acc, 0, 0, 0);
    acc = __builtin_amdgcn_mfma_f32_16x16x32_bf16(ahi, blo, acc, 0, 0, 0);
  }
  int n = n0 + l16;
  float bs = bias[n];
  #pragma unroll
  for (int r=0; r<4; r++)
    Cf[(size_t)(i0 + quad*4 + r)*NPROJ + n] = acc[r] + bs;
}

// ------------- ipa GEMM from cat fragments: split-K x4, 512 blocks ----------------
// C = 4 planes of 512x256 at C + ks*131072; bias added on plane 0 only.
__global__ __launch_bounds__(256) void k_gemm_ipa(
    const short* __restrict__ catA16, const __hip_bfloat16* __restrict__ Bp,
    const float* __restrict__ bias, float* __restrict__ C){
  int tid = threadIdx.x;
  int wave = tid>>6, lane = tid&63;
  int ks = blockIdx.y >> 3;               // 0..3
  int i0 = (blockIdx.y & 7)*64 + wave*16;
  int n0 = blockIdx.x*16;
  int quad = lane>>4, l16 = lane&15;
  floatx4 acc = {};
  const short* abase = catA16 + (size_t)(ks*12)*16384 + (size_t)(i0 + l16)*32 + quad*8;
  const __hip_bfloat16* bbase = Bp + ((size_t)(ks*12*16 + blockIdx.x))*1024 + (size_t)lane*8;
  #pragma unroll
  for (int kc=0; kc<12; kc++){
    shortx8 ahi = *(const shortx8*)(abase + kc*16384);
    shortx8 alo = *(const shortx8*)(abase + kc*16384 + CAT_LO);
    const __hip_bfloat16* bt = bbase + (size_t)kc*16*1024;
    shortx8 bhi = *(const shortx8*)bt;
    shortx8 blo = *(const shortx8*)(bt + 512);
    acc = __builtin_amdgcn_mfma_f32_16x16x32_bf16(ahi, bhi, acc, 0, 0, 0);
    acc = __builtin_amdgcn_mfma_f32_16x16x32_bf16(alo, bhi, acc, 0, 0, 0);
    acc = __builtin_amdgcn_mfma_f32_16x16x32_bf16(ahi, blo, acc, 0, 0, 0);
  }
  float* Cp = C + (size_t)ks*131072;
  int n = n0 + l16;
  float bs = ks ? 0.f : bias[n];
  #pragma unroll
  for (int r=0; r<4; r++)
    Cp[(size_t)(i0 + quad*4 + r)*CSd + n] = acc[r] + bs;
}

// ------------- LN over CS=256 row -------------
__global__ __launch_bounds__(256) void k_addln(
    const float* __restrict__ x, const float* __restrict__ y,
    const float* __restrict__ g, const float* __restrict__ b,
    float* __restrict__ out){
  __shared__ float red[4];
  int row = blockIdx.x, tid = threadIdx.x;
  float v = x[row*CSd + tid];
  if (y) v += y[row*CSd + tid];
  int wid = tid>>6, lane = tid&63;
  float s = wave_sum(v);
  if (lane==0) red[wid] = s;
  __syncthreads();
  float mu = (red[0]+red[1]+red[2]+red[3]) * (1.f/CSd);
  __syncthreads();
  float d = v - mu;
  float s2 = wave_sum(d*d);
  if (lane==0) red[wid] = s2;
  __syncthreads();
  float var = (red[0]+red[1]+red[2]+red[3]) * (1.f/CSd);
  float rs = rsqrtf(var + 1e-5f);
  out[row*CSd + tid] = d*rs*g[tid] + b[tid];
}

// ------------- zn LN: pair_bias (half) + znt bf16 [i][c][j] -------------
// (round-6 version: wpb/g/b staged in LDS — measured 84 us; global-read variant was 175)
__global__ __launch_bounds__(1024, 4) void k_lnz_pb(
    const float* __restrict__ z, const float* __restrict__ g, const float* __restrict__ b,
    const float* __restrict__ wpb, __half* __restrict__ pb, __hip_bfloat16* __restrict__ znt){
  __shared__ float Zt[64*129];       // 33024 B
  __shared__ float wpbht[8*129];     // [h][c] pad-129 (4-way max)
  __shared__ float gl[128], bl[128];
  int tid = threadIdx.x;
  size_t row0 = (size_t)blockIdx.x*64;
  int ib = (int)(row0 >> 9), j0 = (int)(row0 & 511);
  {
    int c = tid>>3, h = tid&7;
    wpbht[h*129 + c] = wpb[tid];
  }
  if (tid < 128){ gl[tid] = g[tid]; bl[tid] = b[tid]; }
  // phase 1: each wave loads one row (512B) per iter as float2
  {
    int w = tid>>6, lane = tid&63;
    #pragma unroll
    for (int it=0; it<4; it++){
      int row = it*16 + w;
      const float2 v = *(const float2*)(z + (row0+row)*(size_t)CZd + lane*2);
      Zt[row*129 + lane*2]     = v.x;
      Zt[row*129 + lane*2 + 1] = v.y;
    }
  }
  __syncthreads();
  // phase 2: stats + in-place normalize + pb (register-resident)
  {
    int r = tid>>4, q = tid&15;
    int rot = 2*(q>>2);
    float S1=0.f, S2=0.f;
    float zv[8];
    #pragma unroll
    for (int i=0; i<8; i++){
      int ii = (i + rot) & 7;
      float v = Zt[r*129 + q*8 + ii];
      zv[i] = v;
      S1 += v; S2 += v*v;
    }
    S1 += __shfl_xor(S1,1); S2 += __shfl_xor(S2,1);
    S1 += __shfl_xor(S1,2); S2 += __shfl_xor(S2,2);
    S1 += __shfl_xor(S1,4); S2 += __shfl_xor(S2,4);
    S1 += __shfl_xor(S1,8); S2 += __shfl_xor(S2,8);
    float mu = S1 * (1.f/128.f);
    float var = S2 * (1.f/128.f) - mu*mu;
    float rs = rsqrtf(var + 1e-5f);
    float d[8] = {};
    #pragma unroll
    for (int i=0; i<8; i++){
      int ii = (i + rot) & 7;
      int c = q*8 + ii;
      float znv = (zv[i]-mu)*rs*gl[c] + bl[c];
      Zt[r*129 + c] = znv;
      #pragma unroll
      for (int h=0; h<8; h++) d[h] += znv * wpbht[h*129 + c];
    }
    #pragma unroll
    for (int h=0; h<8; h++){
      d[h] += __shfl_xor(d[h],1);
      d[h] += __shfl_xor(d[h],2);
      d[h] += __shfl_xor(d[h],4);
      d[h] += __shfl_xor(d[h],8);
    }
    if (q == 0){
      #pragma unroll
      for (int h=0; h<8; h++)
        pb[((size_t)(h*Lq + ib))*Lq + j0 + r] = __float2half(d[h]);
    }
  }
  __syncthreads();
  // phase 3: repack; thread (c = tid>>3, jg = tid&7) packs 8 j -> one dwordx4 store
  {
    int c = tid>>3, jg = tid&7;
    int jb = jg*8;
    unsigned int o[4];
    #pragma unroll
    for (int k=0; k<4; k++){
      float z0 = Zt[(jb+2*k)*129 + c];
      float z1 = Zt[(jb+2*k+1)*129 + c];
      o[k] = ((unsigned int)(unsigned short)f2bf(z0)) |
             (((unsigned int)(unsigned short)f2bf(z1)) << 16);
    }
    unsigned short* zo = (unsigned short*)znt;
    uint4 pk = make_uint4(o[0],o[1],o[2],o[3]);
    *(uint4*)(zo + ((size_t)(ib*128 + c))*512 + j0 + jb) = pk;
  }
}

// ------------- pack Q'/K'/V' in MFMA layouts (vectorized), compute qn/kn -------------
__global__ __launch_bounds__(256) void k_packqkv(
    const float* __restrict__ P, const float* __restrict__ R, const float* __restrict__ t,
    const float* __restrict__ gamma, int zfill,
    float* __restrict__ Qp, __hip_bfloat16* __restrict__ Kp, __hip_bfloat16* __restrict__ Vp,
    float* __restrict__ qn, float* __restrict__ kn){
  int idx = blockIdx.x*256 + threadIdx.x;   // 3*32768
  int region = idx >> 15;
  int rem = idx & 32767;
  if (region == 0){
    int oct = rem & 7, h = (rem>>3)&7, j = rem>>6;
    float v[8] = {0.f,0.f,0.f,0.f,0.f,0.f,0.f,0.f};
    const float* Prow = P + (size_t)j*NPROJ;
    if (oct < 4){
      float4 a = *(const float4*)(Prow + 256 + h*CHd + oct*8);
      float4 b4 = *(const float4*)(Prow + 256 + h*CHd + oct*8 + 4);
      v[0]=a.x; v[1]=a.y; v[2]=a.z; v[3]=a.w; v[4]=b4.x; v[5]=b4.y; v[6]=b4.z; v[7]=b4.w;
    } else if (oct < 6){
      const float* kp = Prow + 864 + h*12;
      float4 k0 = *(const float4*)kp;
      float4 k1 = *(const float4*)(kp+4);
      float4 k2 = *(const float4*)(kp+8);
      float kv[12] = {k0.x,k0.y,k0.z,k0.w,k1.x,k1.y,k1.z,k1.w,k2.x,k2.y,k2.z,k2.w};
      float Rl[9];
      #pragma unroll
      for (int ii=0; ii<9; ii++) Rl[ii] = R[j*9+ii];
      float tv[3] = {t[j*3], t[j*3+1], t[j*3+2]};
      float gvals[12];
      #pragma unroll
      for (int p=0; p<4; p++)
        #pragma unroll
        for (int ax=0; ax<3; ax++)
          gvals[p*3+ax] = Rl[ax*3]*kv[p*3] + Rl[ax*3+1]*kv[p*3+1] + Rl[ax*3+2]*kv[p*3+2] + tv[ax];
      if (oct == 4){
        #pragma unroll
        for (int m=0; m<8; m++) v[m] = gvals[m];
      } else {
        #pragma unroll
        for (int m=0; m<4; m++) v[m] = gvals[8+m];
        float acc = 0.f;
        #pragma unroll
        for (int m=0; m<12; m++) acc += gvals[m]*gvals[m];
        kn[j*Hd + h] = acc;
      }
    } else {
      if (!zfill) return;
    }
    shortx8 hi, lo;
    #pragma unroll
    for (int m=0; m<8; m++){
      short hh = f2bf(v[m]);
      hi[m] = hh; lo[m] = f2bf(v[m] - bf2f(hh));
    }
    int kc = oct>>2, jt = j>>4, l16 = j&15, quad = oct&3;
    size_t base = (size_t)((h*2+kc)*32 + jt)*1024 + (quad*16+l16)*8;
    short* kp16 = (short*)Kp;
    *(shortx8*)(kp16 + base)       = hi;
    *(shortx8*)(kp16 + base + 512) = lo;
  } else if (region == 1){
    int n = rem & 63, h = (rem>>6)&7, jg = rem>>9;
    int jb = jg*8;
    float v[8] = {0.f,0.f,0.f,0.f,0.f,0.f,0.f,0.f};
    if (n < 32){
      #pragma unroll
      for (int m=0; m<8; m++) v[m] = P[(size_t)(jb+m)*NPROJ + 512 + h*CHd + n];
    } else if (n < 56){
      int p = (n-32)/3, ax = (n-32)%3;
      #pragma unroll
      for (int m=0; m<8; m++){
        int j = jb+m;
        const float* vp = P + (size_t)j*NPROJ + 960 + h*24 + p*3;
        const float* Rr = R + j*9 + ax*3;
        v[m] = Rr[0]*vp[0] + Rr[1]*vp[1] + Rr[2]*vp[2] + t[j*3+ax];
      }
    } else {
      if (!zfill) return;
    }
    shortx8 hi, lo;
    #pragma unroll
    for (int m=0; m<8; m++){
      short hh = f2bf(v[m]);
      hi[m] = hh; lo[m] = f2bf(v[m] - bf2f(hh));
    }
    int kc2 = jg>>2, w = n>>4, l16 = n&15, quad = jg&3;
    size_t base = (size_t)((h*16+kc2)*4 + w)*1024 + (quad*16+l16)*8;
    short* vp16 = (short*)Vp;
    *(shortx8*)(vp16 + base)       = hi;
    *(shortx8*)(vp16 + base + 512) = lo;
  } else {
    int oct = rem & 7, h = (rem>>3)&7, i = rem>>6;
    float v[8] = {0.f,0.f,0.f,0.f,0.f,0.f,0.f,0.f};
    const float* Prow = P + (size_t)i*NPROJ;
    if (oct < 4){
      float4 a = *(const float4*)(Prow + h*CHd + oct*8);
      float4 b4 = *(const float4*)(Prow + h*CHd + oct*8 + 4);
      const float sc = WLC*ISC;
      v[0]=a.x*sc; v[1]=a.y*sc; v[2]=a.z*sc; v[3]=a.w*sc;
      v[4]=b4.x*sc; v[5]=b4.y*sc; v[6]=b4.z*sc; v[7]=b4.w*sc;
    } else if (oct < 6){
      const float* qp = Prow + 768 + h*12;
      float4 k0 = *(const float4*)qp;
      float4 k1 = *(const float4*)(qp+4);
      float4 k2 = *(const float4*)(qp+8);
      float kv[12] = {k0.x,k0.y,k0.z,k0.w,k1.x,k1.y,k1.z,k1.w,k2.x,k2.y,k2.z,k2.w};
      float Rl[9];
      #pragma unroll
      for (int ii=0; ii<9; ii++) Rl[ii] = R[i*9+ii];
      float tv[3] = {t[i*3], t[i*3+1], t[i*3+2]};
      float gvals[12];
      #pragma unroll
      for (int p=0; p<4; p++)
        #pragma unroll
        for (int ax=0; ax<3; ax++)
          gvals[p*3+ax] = Rl[ax*3]*kv[p*3] + Rl[ax*3+1]*kv[p*3+1] + Rl[ax*3+2]*kv[p*3+2] + tv[ax];
      float sc = WLC*WCC*gamma[h];
      if (oct == 4){
        #pragma unroll
        for (int m=0; m<8; m++) v[m] = gvals[m]*sc;
      } else {
        #pragma unroll
        for (int m=0; m<4; m++) v[m] = gvals[8+m]*sc;
        float acc = 0.f;
        #pragma unroll
        for (int m=0; m<12; m++) acc += gvals[m]*gvals[m];
        qn[i*Hd + h] = acc;
      }
    } else {
      if (!zfill) return;
    }
    float* qrow = Qp + ((size_t)h*512 + i)*64 + oct*8;
    *(float4*)qrow       = make_float4(v[0],v[1],v[2],v[3]);
    *(float4*)(qrow + 4) = make_float4(v[4],v[5],v[6],v[7]);
  }
}

// ------------- fused attention: 16 q-rows/block, 1024 threads (16 waves) -------------
__global__ __launch_bounds__(1024) void k_attn(
    const float* __restrict__ Qp, const __hip_bfloat16* __restrict__ Kp,
    const __hip_bfloat16* __restrict__ Vp,
    const float* __restrict__ qn, const float* __restrict__ kn,
    const __half* __restrict__ pb, const float* __restrict__ maskb,
    const float* __restrict__ gamma,
    const float* __restrict__ R, const float* __restrict__ t,
    __hip_bfloat16* __restrict__ a16hi,
    short* __restrict__ catA16){
  __shared__ float At[16][516];
  __shared__ short AbfH[16*4*16*8];   // [kc][quad][row][jj]
  __shared__ short AbfL[16*4*16*8];
  __shared__ float Pv[3][16][68];
  __shared__ float Ot[16][36];
  __shared__ float qnL[16];
  int tid = threadIdx.x;
  int i0 = blockIdx.x*16, h = blockIdx.y;
  int wave = tid>>6, lane = tid&63, quad = lane>>4, l16 = lane&15;
  int kg = wave>>2, ng = wave&3;
  float gam = gamma[h];
  float coef = 0.5f*WLC*WCC*gam;
  if (tid < 16) qnL[tid] = qn[(i0+tid)*Hd + h];
  __syncthreads();
  // Q fragments (16 real rows)
  const float* qrow = Qp + ((size_t)h*512 + i0 + l16)*64 + quad*8;
  shortx8 qhi[2], qlo[2];
  #pragma unroll
  for (int kc=0; kc<2; kc++){
    float4 v0 = *(const float4*)(qrow + kc*32);
    float4 v1 = *(const float4*)(qrow + kc*32 + 4);
    float av[8] = {v0.x,v0.y,v0.z,v0.w,v1.x,v1.y,v1.z,v1.w};
    #pragma unroll
    for (int j=0; j<8; j++){
      short hh = f2bf(av[j]);
      qhi[kc][j] = hh; qlo[kc][j] = f2bf(av[j] - bf2f(hh));
    }
  }
  // QK^T: 32 j-tiles over 16 waves, 2 iters
  #pragma unroll
  for (int it=0; it<2; it++){
    int jt = it*16 + wave;
    floatx4 acc = {};
    #pragma unroll
    for (int kc=0; kc<2; kc++){
      const __hip_bfloat16* bt = Kp + (size_t)((h*2+kc)*32 + jt)*1024 + lane*8;
      shortx8 bhi = *(const shortx8*)bt;
      shortx8 blo = *(const shortx8*)(bt + 512);
      acc = __builtin_amdgcn_mfma_f32_16x16x32_bf16(qhi[kc], bhi, acc, 0, 0, 0);
      acc = __builtin_amdgcn_mfma_f32_16x16x32_bf16(qlo[kc], bhi, acc, 0, 0, 0);
      acc = __builtin_amdgcn_mfma_f32_16x16x32_bf16(qhi[kc], blo, acc, 0, 0, 0);
    }
    int j = jt*16 + l16;
    float knj = kn[j*Hd + h];
    float mbj = maskb[j];
    #pragma unroll
    for (int r=0; r<4; r++){
      int i = quad*4 + r;
      float pbv = __half2float(pb[((size_t)(h*Lq) + i0 + i)*Lq + j]);
      At[i][j] = acc[r] + WLC*pbv + mbj - coef*(qnL[i] + knj);
    }
  }
  __syncthreads();
  // softmax: wave w owns row w (16 waves, 16 rows); shuffle-only reductions
  {
    int w = wave;
    float v[8];
    float m = -1e30f;
    #pragma unroll
    for (int k=0; k<8; k++){ v[k] = At[w][lane + 64*k]; m = fmaxf(m, v[k]); }
    #pragma unroll
    for (int msk=32; msk; msk>>=1) m = fmaxf(m, __shfl_xor(m, msk));
    float ssum = 0.f;
    #pragma unroll
    for (int k=0; k<8; k++){ float e = __expf(v[k]-m); v[k]=e; ssum += e; }
    #pragma unroll
    for (int msk=32; msk; msk>>=1) ssum += __shfl_xor(ssum, msk);
    float inv = 1.f/ssum;
    #pragma unroll
    for (int k=0; k<8; k++){
      int cc = lane + 64*k;
      float p = v[k]*inv;
      short hh = f2bf(p);
      short ll = f2bf(p - bf2f(hh));
      a16hi[(((size_t)(i0+w)*16 + (cc>>5))*8 + h)*32 + (cc&31)] = s2b(hh);
      int off = ((((cc>>5)*4 + ((cc>>3)&3))*16 + w)<<3) + (cc&7);
      AbfH[off] = hh;
      AbfL[off] = ll;
    }
  }
  __syncthreads();
  // AV: wave (kg, ng): 4 kc each, n-tile ng; 3 partial groups reduce via LDS
  floatx4 acc2 = {};
  #pragma unroll
  for (int kk=0; kk<4; kk++){
    int kc2 = kg*4 + kk;
    int aoff = (((kc2*4 + quad)*16 + l16))<<3;
    shortx8 ahi = *(const shortx8*)&AbfH[aoff];
    shortx8 alo = *(const shortx8*)&AbfL[aoff];
    const __hip_bfloat16* bt = Vp + (size_t)((h*16+kc2)*4 + ng)*1024 + lane*8;
    shortx8 bhi = *(const shortx8*)bt;
    shortx8 blo = *(const shortx8*)(bt + 512);
    acc2 = __builtin_amdgcn_mfma_f32_16x16x32_bf16(ahi, bhi, acc2, 0, 0, 0);
    acc2 = __builtin_amdgcn_mfma_f32_16x16x32_bf16(alo, bhi, acc2, 0, 0, 0);
    acc2 = __builtin_amdgcn_mfma_f32_16x16x32_bf16(ahi, blo, acc2, 0, 0, 0);
  }
  if (kg > 0){
    #pragma unroll
    for (int r=0;r<4;r++) Pv[kg-1][quad*4+r][ng*16+l16] = acc2[r];
  }
  __syncthreads();
  if (kg == 0){
    int n = ng*16 + l16;
    #pragma unroll
    for (int r=0;r<4;r++){
      int i = quad*4+r;
      float v = acc2[r] + Pv[0][i][n] + Pv[1][i][n] + Pv[2][i][n];
      if (n < 32) cat_store(catA16, h*CHd + n, i0+i, v);
      else        Ot[i][n-32] = v;
    }
  }
  __syncthreads();
  if (tid < 128){
    int i = tid>>3, p = tid&7, gi = i0+i;
    float o0 = Ot[i][p*3], o1 = Ot[i][p*3+1], o2 = Ot[i][p*3+2];
    float d0 = o0 - t[gi*3], d1 = o1 - t[gi*3+1], d2 = o2 - t[gi*3+2];
    const float* Rm = R + gi*9;
    float l0 = Rm[0]*d0 + Rm[3]*d1 + Rm[6]*d2;
    float l1 = Rm[1]*d0 + Rm[4]*d1 + Rm[7]*d2;
    float l2 = Rm[2]*d0 + Rm[5]*d1 + Rm[8]*d2;
    int kb = 256 + h*24 + p*3;
    cat_store(catA16, kb,   gi, l0);
    cat_store(catA16, kb+1, gi, l1);
    cat_store(catA16, kb+2, gi, l2);
    cat_store(catA16, 448 + h*8 + p, gi, sqrtf(l0*l0 + l1*l1 + l2*l2 + 1e-8f));
  }
}

// ------------- opair = a @ zn via MFMA (a hi-only), 512 threads -------------
__global__ __launch_bounds__(512) void k_opair_mfma(
    const __hip_bfloat16* __restrict__ a16hi,
    const __hip_bfloat16* __restrict__ znt, short* __restrict__ catA16){
  int i = blockIdx.x;
  int tid = threadIdx.x;
  int wave = tid>>6, lane = tid&63, quad = lane>>4, l16 = lane&15;
  int nt = wave;
  floatx4 acc = {};
  const __hip_bfloat16* abase_h = a16hi + ((size_t)i*16*8 + (l16&7))*32 + quad*8;
  const __hip_bfloat16* zb = znt + ((size_t)i*128 + nt*16 + l16)*512 + quad*8;
  #pragma unroll
  for (int kt=0; kt<16; kt++){
    shortx8 ah = *(const shortx8*)(abase_h + kt*256);
    shortx8 b0 = *(const shortx8*)(zb + kt*32);
    acc = __builtin_amdgcn_mfma_f32_16x16x32_bf16(ah, b0, acc, 0, 0, 0);
  }
  if (quad < 2){
    #pragma unroll
    for (int r=0; r<4; r++){
      int h = quad*4 + r;
      cat_store(catA16, 512 + h*CZd + nt*16 + l16, i, acc[r]);
    }
  }
}

// ------------- mega: LN + 3 GEMMs + LN + upd + frame update (1024 threads) ---------
__device__ __forceinline__ void gemm_bf16w(
    const short* __restrict__ AHp, const short* __restrict__ ALp,
    short* __restrict__ OH, short* __restrict__ OL, float (*Yf)[260],
    const __hip_bfloat16* __restrict__ Wp, const float* __restrict__ bias,
    bool relu, int tid){
  int wave = tid>>6, lane = tid&63, quad = lane>>4, l16 = lane&15;
  floatx4 acc = {};
  #pragma unroll
  for (int kc=0; kc<8; kc++){
    int aoff = (((kc*4 + quad)*16 + l16))<<3;
    shortx8 ahi = *(const shortx8*)&AHp[aoff];
    shortx8 alo = *(const shortx8*)&ALp[aoff];
    const __hip_bfloat16* bt = Wp + (size_t)(kc*16 + wave)*1024 + lane*8;
    shortx8 bhi = *(const shortx8*)bt;
    shortx8 blo = *(const shortx8*)(bt + 512);
    acc = __builtin_amdgcn_mfma_f32_16x16x32_bf16(ahi, bhi, acc, 0, 0, 0);
    acc = __builtin_amdgcn_mfma_f32_16x16x32_bf16(alo, bhi, acc, 0, 0, 0);
    acc = __builtin_amdgcn_mfma_f32_16x16x32_bf16(ahi, blo, acc, 0, 0, 0);
  }
  int n = wave*16 + l16;
  float bs = bias[n];
  #pragma unroll
  for (int r=0;r<4;r++){
    float v = acc[r] + bs;
    if (relu) v = fmaxf(v, 0.f);
    int row = quad*4 + r;
    if (OH){
      short hh = f2bf(v);
      int off = ((((n>>5)*4 + ((n>>3)&3))*16 + row)<<3) + (n&7);
      OH[off] = hh;
      OL[off] = f2bf(v - bf2f(hh));
    } else {
      Yf[row][n] = v;
    }
  }
}

__global__ __launch_bounds__(1024) void k_mega(
    float* __restrict__ scb, const float* __restrict__ ipa,
    const float* __restrict__ gi_, const float* __restrict__ bi_,
    const __hip_bfloat16* __restrict__ W1, const float* __restrict__ c1,
    const __hip_bfloat16* __restrict__ W2, const float* __restrict__ c2,
    const __hip_bfloat16* __restrict__ W3, const float* __restrict__ c3,
    const float* __restrict__ gt_, const float* __restrict__ bt_,
    const float* __restrict__ mask,
    const float* __restrict__ wbb, const float* __restrict__ bbb,
    float* __restrict__ R, float* __restrict__ t, short* __restrict__ scA16){
  __shared__ float As[16][260], Bs[16][260];
  __shared__ short AH[2][4096], AL[2][4096];
  __shared__ float rA[16][33], rB[16][33];
  __shared__ float mv[16][2];
  __shared__ float u6p[16][6][2];
  int tid = threadIdx.x;
  int i0 = blockIdx.x*16;
  int r = (tid>>5)&15, c5 = tid&31, c0 = c5*8;
  float v[8];
  // stage 0: LN(sc + ipa0+ipa1+ipa2+ipa3)
  if (tid < 512){
    const float* sr = scb + (size_t)(i0+r)*CSd + c0;
    const float* p0 = ipa + (size_t)(i0+r)*CSd + c0;
    const float* p1 = p0 + 131072;
    const float* p2 = p0 + 262144;
    const float* p3 = p0 + 393216;
    float s1=0.f, s2=0.f;
    #pragma unroll
    for (int k2=0;k2<8;k2++){
      float x = sr[k2] + p0[k2] + p1[k2] + p2[k2] + p3[k2];
      v[k2]=x; s1+=x; s2+=x*x;
    }
    rA[r][c5]=s1; rB[r][c5]=s2;
  }
  __syncthreads();
  if (tid<16){
    float s1=0.f,s2=0.f;
    #pragma unroll
    for (int c=0;c<32;c++){ s1+=rA[tid][c]; s2+=rB[tid][c]; }
    float mu = s1*(1.f/CSd), var = s2*(1.f/CSd) - mu*mu;
    mv[tid][0]=mu; mv[tid][1]=rsqrtf(var+1e-5f);
  }
  __syncthreads();
  if (tid < 512){
    float mu=mv[r][0], rs=mv[r][1];
    #pragma unroll
    for (int k2=0;k2<8;k2++){
      int col = c0+k2;
      float o = (v[k2]-mu)*rs*gi_[col] + bi_[col];
      As[r][col] = o;
      short hh = f2bf(o);
      int off = ((((col>>5)*4 + ((col>>3)&3))*16 + r)<<3) + (col&7);
      AH[0][off] = hh;
      AL[0][off] = f2bf(o - bf2f(hh));
    }
  }
  __syncthreads();
  gemm_bf16w(AH[0], AL[0], AH[1], AL[1], nullptr, W1, c1, true, tid);
  __syncthreads();
  gemm_bf16w(AH[1], AL[1], AH[0], AL[0], nullptr, W2, c2, true, tid);
  __syncthreads();
  gemm_bf16w(AH[0], AL[0], nullptr, nullptr, Bs, W3, c3, false, tid);
  __syncthreads();
  // stage 4: LN(sc_new + tr3*mask)
  if (tid < 512){
    float mk = mask[i0+r];
    float s1=0.f, s2=0.f;
    #pragma unroll
    for (int k2=0;k2<8;k2++){ float x = As[r][c0+k2] + Bs[r][c0+k2]*mk; v[k2]=x; s1+=x; s2+=x*x; }
    rA[r][c5]=s1; rB[r][c5]=s2;
  }
  __syncthreads();
  if (tid<16){
    float s1=0.f,s2=0.f;
    #pragma unroll
    for (int c=0;c<32;c++){ s1+=rA[tid][c]; s2+=rB[tid][c]; }
    float mu = s1*(1.f/CSd), var = s2*(1.f/CSd) - mu*mu;
    mv[tid][0]=mu; mv[tid][1]=rsqrtf(var+1e-5f);
  }
  __syncthreads();
  if (tid < 512){
    float mu=mv[r][0], rs=mv[r][1];
    float* out = scb + (size_t)(i0+r)*CSd + c0;
    shortx8 hi, lo;
    #pragma unroll
    for (int k2=0;k2<8;k2++){
      int col = c0+k2;
      float o = (v[k2]-mu)*rs*gt_[col] + bt_[col];
      As[r][col] = o;
      out[k2] = o;
      short hh = f2bf(o);
      hi[k2] = hh; lo[k2] = f2bf(o - bf2f(hh));
    }
    size_t off = ((size_t)((c5>>2)*512 + i0 + r)*4 + (c5&3))*8;
    *(shortx8*)(scA16 + off)          = hi;
    *(shortx8*)(scA16 + off + 131072) = lo;
  }
  __syncthreads();
  // stage 5: upd (192-thread k-split) + quat update
  if (tid < 192){
    int rr = tid/12, o = (tid%12)>>1, half = tid&1;
    float acc = half ? 0.f : bbb[o];
    int kb = half*128;
    for (int k2=kb; k2<kb+128; k2++) acc += As[rr][k2]*wbb[k2*6+o];
    u6p[rr][o][half] = acc;
  }
  __syncthreads();
  if (tid < 16){
    int gidx = i0 + tid;
    float uu[6];
    #pragma unroll
    for (int o=0;o<6;o++) uu[o] = u6p[tid][o][0] + u6p[tid][o][1];
    float bq = uu[0], cq = uu[1], dq = uu[2];
    float norm = sqrtf(1.f + bq*bq + cq*cq + dq*dq);
    float a = 1.f/norm, b_ = bq/norm, c_ = cq/norm, d_ = dq/norm;
    float dR[9];
    dR[0] = a*a + b_*b_ - c_*c_ - d_*d_; dR[1] = 2.f*(b_*c_ - a*d_); dR[2] = 2.f*(b_*d_ + a*c_);
    dR[3] = 2.f*(b_*c_ + a*d_); dR[4] = a*a - b_*b_ + c_*c_ - d_*d_; dR[5] = 2.f*(c_*d_ - a*b_);
    dR[6] = 2.f*(b_*d_ - a*c_); dR[7] = 2.f*(c_*d_ + a*b_); dR[8] = a*a - b_*b_ - c_*c_ + d_*d_;
    float mk = mask[gidx];
    float dt0 = uu[3]*mk, dt1 = uu[4]*mk, dt2 = uu[5]*mk;
    float Rm[9];
    #pragma unroll
    for (int ii=0; ii<9; ii++) Rm[ii] = R[gidx*9+ii];
    t[gidx*3]   += Rm[0]*dt0 + Rm[1]*dt1 + Rm[2]*dt2;
    t[gidx*3+1] += Rm[3]*dt0 + Rm[4]*dt1 + Rm[5]*dt2;
    t[gidx*3+2] += Rm[6]*dt0 + Rm[7]*dt1 + Rm[8]*dt2;
    #pragma unroll
    for (int ii=0; ii<3; ii++)
      #pragma unroll
      for (int jj=0; jj<3; jj++)
        R[gidx*9 + ii*3 + jj] = Rm[ii*3]*dR[jj] + Rm[ii*3+1]*dR[3+jj] + Rm[ii*3+2]*dR[6+jj];
  }
}

// ------------- final output write -------------
__global__ __launch_bounds__(256) void k_writeout(
    const float* __restrict__ sc, const float* __restrict__ R, const float* __restrict__ t,
    float* __restrict__ out){
  int idx = blockIdx.x*256 + threadIdx.x;
  if      (idx < 131072) out[idx] = sc[idx];
  else if (idx < 135680) out[idx] = R[idx-131072];
  else if (idx < 137216) out[idx] = t[idx-135680];
}

extern "C" void kernel_launch(void* const* d_in, const int* in_sizes, int n_in,
                              void* d_out, int out_size, void* d_ws, size_t ws_size,
                              hipStream_t stream){
  const float* s      = (const float*)d_in[0];
  const float* z      = (const float*)d_in[1];
  const float* mask   = (const float*)d_in[2];
  const float* ln_s_g = (const float*)d_in[3];
  const float* ln_s_b = (const float*)d_in[4];
  const float* ln_z_g = (const float*)d_in[5];
  const float* ln_z_b = (const float*)d_in[6];
  const float* w_init = (const float*)d_in[7];
  const float* b_init = (const float*)d_in[8];
  const float* ln_ipa_g = (const float*)d_in[9];
  const float* ln_ipa_b = (const float*)d_in[10];
  const float* ln_tr_g  = (const float*)d_in[11];
  const float* ln_tr_b  = (const float*)d_in[12];
  const float* wq = (const float*)d_in[13]; const float* bq = (const float*)d_in[14];
  const float* wk = (const float*)d_in[15]; const float* bk = (const float*)d_in[16];
  const float* wv = (const float*)d_in[17]; const float* bv = (const float*)d_in[18];
  const float* wqp = (const float*)d_in[19]; const float* bqp = (const float*)d_in[20];
  const float* wkp = (const float*)d_in[21]; const float* bkp = (const float*)d_in[22];
  const float* wvp = (const float*)d_in[23]; const float* bvp = (const float*)d_in[24];
  const float* wpb = (const float*)d_in[25];
  const float* head_w = (const float*)d_in[26];
  const float* wo = (const float*)d_in[27]; const float* bo = (const float*)d_in[28];
  const float* wt1 = (const float*)d_in[29]; const float* bt1 = (const float*)d_in[30];
  const float* wt2 = (const float*)d_in[31]; const float* bt2 = (const float*)d_in[32];
  const float* wt3 = (const float*)d_in[33]; const float* bt3 = (const float*)d_in[34];
  const float* wbb = (const float*)d_in[35]; const float* bbb = (const float*)d_in[36];

  float* W = (float*)d_ws;
  float* scb   = W + OFF_SC;
  __half*  pbb  = (__half*)(W + OFF_PB);
  float* Pb    = W + OFF_P;
  float* qnb   = W + OFF_QN;
  float* knb   = W + OFF_KN;
  __hip_bfloat16* a16hi = (__hip_bfloat16*)(W + OFF_A16);
  short* catA16 = (short*)(W + OFF_CAT);
  float* s0b   = W + OFF_S0;
  float* Rb    = W + OFF_R;
  float* tb    = W + OFF_T;
  float* gammab= W + OFF_GAMMA;
  float* maskb = W + OFF_MASKB;
  float* bcat  = W + OFF_BCAT;
  __hip_bfloat16* WinitP = (__hip_bfloat16*)(W + OFF_WINITP);
  __hip_bfloat16* Wt1P   = (__hip_bfloat16*)(W + OFF_WT1P);
  __hip_bfloat16* Wt2P   = (__hip_bfloat16*)(W + OFF_WT2P);
  __hip_bfloat16* Wt3P   = (__hip_bfloat16*)(W + OFF_WT3P);
  __hip_bfloat16* WoP    = (__hip_bfloat16*)(W + OFF_WOP);
  __hip_bfloat16* WcatP  = (__hip_bfloat16*)(W + OFF_WCATP);
  float* Qp = W + OFF_QP;
  __hip_bfloat16* Kp = (__hip_bfloat16*)(W + OFF_KP);
  __hip_bfloat16* Vp = (__hip_bfloat16*)(W + OFF_VP);
  short* scA16 = (short*)(W + OFF_SCA16);
  __hip_bfloat16* znt = (__hip_bfloat16*)(W + OFF_ZNT);

  k_setup<<<9, 256, 0, stream>>>(bq,bk,bv,bqp,bkp,bvp, head_w, mask, bcat, gammab, maskb, Rb, tb);
  k_pack_cat<<<CSd*NPROJ/256, 256, 0, stream>>>(wq,wk,wv,wqp,wkp,wvp, WcatP);
  k_pack<<<256,  256, 0, stream>>>(w_init, CSd, CSd, WinitP);
  k_pack<<<1536, 256, 0, stream>>>(wo, CATd, CSd, WoP);
  k_pack<<<256,  256, 0, stream>>>(wt1, CSd, CSd, Wt1P);
  k_pack<<<256,  256, 0, stream>>>(wt2, CSd, CSd, Wt2P);
  k_pack<<<256,  256, 0, stream>>>(wt3, CSd, CSd, Wt3P);

  k_addln<<<Lq, 256, 0, stream>>>(s, nullptr, ln_s_g, ln_s_b, s0b);
  k_gemm_mfma<4><<<dim3(4,8), 256, 0, stream>>>(s0b, CSd, WinitP, CSd, b_init, scb, 0, nullptr);
  k_cvtA<<<64, 256, 0, stream>>>(scb, scA16);
  k_lnz_pb<<<Lq*Lq/64, 1024, 0, stream>>>(z, ln_z_g, ln_z_b, wpb, pbb, znt);

  for (int it=0; it<8; ++it){
    k_gemm_proj<<<dim3(72,8), 256, 0, stream>>>(scA16, WcatP, bcat, Pb);
    k_packqkv<<<384, 256, 0, stream>>>(Pb, Rb, tb, gammab, (it==0)?1:0,
                                       Qp, Kp, Vp, qnb, knb);
    k_attn<<<dim3(32,8), 1024, 0, stream>>>(Qp, Kp, Vp, qnb, knb, pbb, maskb, gammab, Rb, tb,
                                            a16hi, catA16);
    k_opair_mfma<<<Lq, 512, 0, stream>>>(a16hi, znt, catA16);
    k_gemm_ipa<<<dim3(16,32), 256, 0, stream>>>(catA16, WoP, bo, Pb);
    k_mega<<<32, 1024, 0, stream>>>(scb, Pb, ln_ipa_g, ln_ipa_b,
                                    Wt1P, bt1, Wt2P, bt2, Wt3P, bt3,
                                    ln_tr_g, ln_tr_b, mask, wbb, bbb, Rb, tb, scA16);
  }
  k_writeout<<<536, 256, 0, stream>>>(scb, Rb, tb, (float*)d_out);
}

// Round 9
// 820.545 us; speedup vs baseline: 1.1187x; 1.0151x over previous
//
#include <hip/hip_runtime.h>
#include <hip/hip_bf16.h>
#include <hip/hip_fp16.h>
#include <math.h>

#define Lq 512
#define CSd 256
#define CZd 128
#define Hd 8
#define CHd 32
#define PQd 4
#define PVd 8
#define CATd 1536
#define NPROJ 1152

typedef __attribute__((ext_vector_type(4))) float floatx4;
typedef __attribute__((ext_vector_type(8))) short shortx8;

// ---------------- ws layout (float offsets) ----------------
#define OFF_SC      0         // 131072
#define OFF_PB      393216    // 1048576 (half)
#define OFF_P       1441792   // 589824  (P, then reused as 4 ipa planes 4*131072)
#define OFF_QN      2031616   // 4096
#define OFF_KN      2035712   // 4096
#define OFF_A16     2039808   // 2097152 (a16hi only)
#define OFF_CAT     4136960   // 786432 floats = catA16: hi plane 786432 shorts + lo plane
#define OFF_S0      4923392   // 131072
#define OFF_R       5054464   // 4608
#define OFF_T       5059072   // 1536
#define OFF_GAMMA   5060608   // 8
#define OFF_MASKB   5060616   // 512
#define OFF_BCAT    5061128   // 1152
#define OFF_WINITP  5062280   // 65536
#define OFF_WT1P    5127816   // 65536
#define OFF_WT2P    5193352   // 65536
#define OFF_WT3P    5258888   // 65536
#define OFF_WOP     5324424   // 393216
#define OFF_WCATP   5717640   // 294912
#define OFF_QP      6012552   // 262144 (fp32)
#define OFF_KP      6274696   // 262144 (=524288 bf16)
#define OFF_VP      6536840   // 262144 (=524288 bf16)
#define OFF_SCA16   6798984   // 131072 (=262144 shorts: hi plane 131072 + lo plane)
#define OFF_ZNT     6930056   // 16777216 (=33554432 bf16)  [i][c][j]

#define CAT_LO 786432

#define WLC 0.57735026918962576f
#define WCC 0.23570226039551584f
#define ISC 0.17677669529663687f

__device__ __forceinline__ float wave_sum(float v){
  #pragma unroll
  for (int m=32; m; m>>=1) v += __shfl_xor(v, m);
  return v;
}
__device__ __forceinline__ short f2bf(float v){
  __hip_bfloat16 h = (__hip_bfloat16)v;
  return __builtin_bit_cast(short, h);
}
__device__ __forceinline__ float bf2f(short s){
  unsigned u = ((unsigned)(unsigned short)s) << 16;
  return __builtin_bit_cast(float, u);
}
__device__ __forceinline__ __hip_bfloat16 s2b(short s){
  return __builtin_bit_cast(__hip_bfloat16, s);
}
// store one (row, col k) element of cat in MFMA-A hi/lo fragment layout
__device__ __forceinline__ void cat_store(short* __restrict__ catA16, int k, int row, float v){
  size_t off = (((size_t)(k>>5)*512 + row)*4 + ((k>>3)&3))*8 + (k&7);
  short hh = f2bf(v);
  catA16[off]          = hh;
  catA16[off + CAT_LO] = f2bf(v - bf2f(hh));
}

// ------------- setup -------------
__global__ __launch_bounds__(256) void k_setup(
    const float* __restrict__ bq, const float* __restrict__ bk, const float* __restrict__ bv,
    const float* __restrict__ bqp, const float* __restrict__ bkp, const float* __restrict__ bvp,
    const float* __restrict__ head_w, const float* __restrict__ mask,
    float* __restrict__ bcat, float* __restrict__ gamma,
    float* __restrict__ maskb, float* __restrict__ R, float* __restrict__ t){
  int k = blockIdx.x*256 + threadIdx.x;
  if (k < NPROJ){
    float v;
    if      (k < 256) v = bq[k];
    else if (k < 512) v = bk[k-256];
    else if (k < 768) v = bv[k-512];
    else if (k < 864) v = bqp[k-768];
    else if (k < 960) v = bkp[k-864];
    else              v = bvp[k-960];
    bcat[k] = v;
    return;
  }
  k -= NPROJ;
  if (k < Hd){ gamma[k] = log1pf(expf(head_w[k])); return; }
  k -= Hd;
  if (k < Lq){ maskb[k] = (mask[k] - 1.f)*1e9f; return; }
  k -= Lq;
  if (k < Lq){
    #pragma unroll
    for (int ii=0; ii<9; ii++) R[k*9+ii] = (ii==0||ii==4||ii==8) ? 1.f : 0.f;
    t[k*3] = 0.f; t[k*3+1] = 0.f; t[k*3+2] = 0.f;
  }
}

// ------------- pack helpers -------------
__device__ __forceinline__ void pack_one(
    const float* __restrict__ W, int N, __hip_bfloat16* __restrict__ out, int idx){
  int j = idx & 7, lane = (idx>>3) & 63, rest = idx >> 9;
  int nt = N >> 4;
  int tn = rest % nt, tk = rest / nt;
  int k = tk*32 + (lane>>4)*8 + j;
  int n = tn*16 + (lane&15);
  float v = W[(size_t)k*N + n];
  short h = f2bf(v);
  short l = f2bf(v - bf2f(h));
  size_t base = (size_t)rest*1024 + (idx & 511);
  out[base]       = s2b(h);
  out[base + 512] = s2b(l);
}

// ------------- fused weight packing (all 6 weights in one launch) -------------
__global__ __launch_bounds__(256) void k_packall(
    const float* __restrict__ wq, const float* __restrict__ wk, const float* __restrict__ wv,
    const float* __restrict__ wqp, const float* __restrict__ wkp, const float* __restrict__ wvp,
    const float* __restrict__ w_init, const float* __restrict__ wo,
    const float* __restrict__ wt1, const float* __restrict__ wt2, const float* __restrict__ wt3,
    __hip_bfloat16* __restrict__ WcatP, __hip_bfloat16* __restrict__ WinitP,
    __hip_bfloat16* __restrict__ WoP, __hip_bfloat16* __restrict__ Wt1P,
    __hip_bfloat16* __restrict__ Wt2P, __hip_bfloat16* __restrict__ Wt3P){
  int idx = blockIdx.x*256 + threadIdx.x;
  if (idx < CSd*NPROJ){
    int j = idx & 7, lane = (idx>>3) & 63, rest = idx >> 9;
    const int nt = NPROJ >> 4;
    int tn = rest % nt, tk = rest / nt;
    int k = tk*32 + (lane>>4)*8 + j;
    int n = tn*16 + (lane&15);
    float v;
    if      (n < 256) v = wq[k*256 + n];
    else if (n < 512) v = wk[k*256 + n-256];
    else if (n < 768) v = wv[k*256 + n-512];
    else if (n < 864) v = wqp[k*96 + n-768];
    else if (n < 960) v = wkp[k*96 + n-864];
    else              v = wvp[k*192 + n-960];
    short h = f2bf(v);
    short l = f2bf(v - bf2f(h));
    size_t base = (size_t)rest*1024 + (idx & 511);
    WcatP[base]       = s2b(h);
    WcatP[base + 512] = s2b(l);
    return;
  }
  idx -= CSd*NPROJ;
  if (idx < CSd*CSd){ pack_one(w_init, CSd, WinitP, idx); return; }
  idx -= CSd*CSd;
  if (idx < CATd*CSd){ pack_one(wo, CSd, WoP, idx); return; }
  idx -= CATd*CSd;
  if (idx < CSd*CSd){ pack_one(wt1, CSd, Wt1P, idx); return; }
  idx -= CSd*CSd;
  if (idx < CSd*CSd){ pack_one(wt2, CSd, Wt2P, idx); return; }
  idx -= CSd*CSd;
  if (idx < CSd*CSd){ pack_one(wt3, CSd, Wt3P, idx); return; }
}

// ------------- split-precision MFMA GEMM (fp32 A); NST = 16-col tiles per block ----
template<int NST>
__global__ __launch_bounds__(256) void k_gemm_mfma(
    const float* __restrict__ A, int K,
    const __hip_bfloat16* __restrict__ Bp, int N,
    const float* __restrict__ bias,
    float* __restrict__ Cf,
    int relu, const float* __restrict__ rowscale){
  int tid = threadIdx.x;
  int wave = tid>>6, lane = tid&63;
  int i0 = blockIdx.y*64 + wave*16;
  int n0 = blockIdx.x*(NST*16);
  int quad = lane>>4, l16 = lane&15;
  floatx4 acc[NST] = {};
  const int ntiles = N >> 4;
  const float* arow = A + (size_t)(i0 + l16)*K + quad*8;
  const __hip_bfloat16* bbase = Bp + ((size_t)(n0>>4))*1024 + (size_t)(lane&63)*8;
  for (int k0=0; k0<K; k0+=32){
    float4 v0 = *(const float4*)(arow + k0);
    float4 v1 = *(const float4*)(arow + k0 + 4);
    float av[8] = {v0.x,v0.y,v0.z,v0.w,v1.x,v1.y,v1.z,v1.w};
    shortx8 ahi, alo;
    #pragma unroll
    for (int j=0; j<8; j++){
      short h = f2bf(av[j]);
      ahi[j] = h;
      alo[j] = f2bf(av[j] - bf2f(h));
    }
    const __hip_bfloat16* bt = bbase + (size_t)(k0>>5)*ntiles*1024;
    #pragma unroll
    for (int s=0; s<NST; s++){
      shortx8 bhi = *(const shortx8*)(bt + s*1024);
      shortx8 blo = *(const shortx8*)(bt + s*1024 + 512);
      acc[s] = __builtin_amdgcn_mfma_f32_16x16x32_bf16(ahi, bhi, acc[s], 0, 0, 0);
      acc[s] = __builtin_amdgcn_mfma_f32_16x16x32_bf16(alo, bhi, acc[s], 0, 0, 0);
      acc[s] = __builtin_amdgcn_mfma_f32_16x16x32_bf16(ahi, blo, acc[s], 0, 0, 0);
    }
  }
  #pragma unroll
  for (int s=0; s<NST; s++){
    int n = n0 + s*16 + l16;
    float bs = bias ? bias[n] : 0.f;
    #pragma unroll
    for (int r=0; r<4; r++){
      int m = i0 + quad*4 + r;
      float v = acc[s][r] + bs;
      if (relu) v = fmaxf(v, 0.f);
      if (rowscale) v *= rowscale[m];
      Cf[(size_t)m*N + n] = v;
    }
  }
}

// ------------- convert sc (fp32) -> scA16 MFMA-A hi/lo fragments -------------
__global__ __launch_bounds__(256) void k_cvtA(
    const float* __restrict__ sc, short* __restrict__ scA16){
  int idx = blockIdx.x*256 + threadIdx.x;   // 16384 = 512*32
  int i = idx>>5, c5 = idx&31;
  int c0 = c5*8, kc = c5>>2, quad = c5&3;
  float4 v0 = *(const float4*)(sc + (size_t)i*CSd + c0);
  float4 v1 = *(const float4*)(sc + (size_t)i*CSd + c0 + 4);
  float av[8] = {v0.x,v0.y,v0.z,v0.w,v1.x,v1.y,v1.z,v1.w};
  shortx8 hi, lo;
  #pragma unroll
  for (int j=0; j<8; j++){
    short h = f2bf(av[j]);
    hi[j] = h; lo[j] = f2bf(av[j] - bf2f(h));
  }
  size_t off = ((size_t)(kc*512 + i)*4 + quad)*8;
  *(shortx8*)(scA16 + off)          = hi;
  *(shortx8*)(scA16 + off + 131072) = lo;
}

// ------------- proj GEMM reading pre-packed A fragments; 16-col tiles, 576 blocks ---
__global__ __launch_bounds__(256) void k_gemm_proj(
    const short* __restrict__ scA16,
    const __hip_bfloat16* __restrict__ Bp,
    const float* __restrict__ bias,
    float* __restrict__ Cf){
  int tid = threadIdx.x;
  int wave = tid>>6, lane = tid&63;
  int i0 = blockIdx.y*64 + wave*16;
  int n0 = blockIdx.x*16;
  int quad = lane>>4, l16 = lane&15;
  floatx4 acc = {};
  const short* abase = scA16 + ((size_t)(i0 + l16)*4 + quad)*8;
  const __hip_bfloat16* bbase = Bp + (size_t)blockIdx.x*1024 + (size_t)lane*8;
  #pragma unroll
  for (int kc=0; kc<8; kc++){
    shortx8 ahi = *(const shortx8*)(abase + kc*16384);
    shortx8 alo = *(const shortx8*)(abase + kc*16384 + 131072);
    const __hip_bfloat16* bt = bbase + (size_t)kc*72*1024;
    shortx8 bhi = *(const shortx8*)bt;
    shortx8 blo = *(const shortx8*)(bt + 512);
    acc = __builtin_amdgcn_mfma_f32_16x16x32_bf16(ahi, bhi, acc, 0, 0, 0);
    acc = __builtin_amdgcn_mfma_f32_16x16x32_bf16(alo, bhi, acc, 0, 0, 0);
    acc = __builtin_amdgcn_mfma_f32_16x16x32_bf16(ahi, blo, acc, 0, 0, 0);
  }
  int n = n0 + l16;
  float bs = bias[n];
  #pragma unroll
  for (int r=0; r<4; r++)
    Cf[(size_t)(i0 + quad*4 + r)*NPROJ + n] = acc[r] + bs;
}

// ------------- ipa GEMM from cat fragments: split-K x4, 512 blocks ----------------
__global__ __launch_bounds__(256) void k_gemm_ipa(
    const short* __restrict__ catA16, const __hip_bfloat16* __restrict__ Bp,
    const float* __restrict__ bias, float* __restrict__ C){
  int tid = threadIdx.x;
  int wave = tid>>6, lane = tid&63;
  int ks = blockIdx.y >> 3;               // 0..3
  int i0 = (blockIdx.y & 7)*64 + wave*16;
  int n0 = blockIdx.x*16;
  int quad = lane>>4, l16 = lane&15;
  floatx4 acc = {};
  const short* abase = catA16 + (size_t)(ks*12)*16384 + (size_t)(i0 + l16)*32 + quad*8;
  const __hip_bfloat16* bbase = Bp + ((size_t)(ks*12*16 + blockIdx.x))*1024 + (size_t)lane*8;
  #pragma unroll
  for (int kc=0; kc<12; kc++){
    shortx8 ahi = *(const shortx8*)(abase + kc*16384);
    shortx8 alo = *(const shortx8*)(abase + kc*16384 + CAT_LO);
    const __hip_bfloat16* bt = bbase + (size_t)kc*16*1024;
    shortx8 bhi = *(const shortx8*)bt;
    shortx8 blo = *(const shortx8*)(bt + 512);
    acc = __builtin_amdgcn_mfma_f32_16x16x32_bf16(ahi, bhi, acc, 0, 0, 0);
    acc = __builtin_amdgcn_mfma_f32_16x16x32_bf16(alo, bhi, acc, 0, 0, 0);
    acc = __builtin_amdgcn_mfma_f32_16x16x32_bf16(ahi, blo, acc, 0, 0, 0);
  }
  float* Cp = C + (size_t)ks*131072;
  int n = n0 + l16;
  float bs = ks ? 0.f : bias[n];
  #pragma unroll
  for (int r=0; r<4; r++)
    Cp[(size_t)(i0 + quad*4 + r)*CSd + n] = acc[r] + bs;
}

// ------------- LN over CS=256 row -------------
__global__ __launch_bounds__(256) void k_addln(
    const float* __restrict__ x, const float* __restrict__ y,
    const float* __restrict__ g, const float* __restrict__ b,
    float* __restrict__ out){
  __shared__ float red[4];
  int row = blockIdx.x, tid = threadIdx.x;
  float v = x[row*CSd + tid];
  if (y) v += y[row*CSd + tid];
  int wid = tid>>6, lane = tid&63;
  float s = wave_sum(v);
  if (lane==0) red[wid] = s;
  __syncthreads();
  float mu = (red[0]+red[1]+red[2]+red[3]) * (1.f/CSd);
  __syncthreads();
  float d = v - mu;
  float s2 = wave_sum(d*d);
  if (lane==0) red[wid] = s2;
  __syncthreads();
  float var = (red[0]+red[1]+red[2]+red[3]) * (1.f/CSd);
  float rs = rsqrtf(var + 1e-5f);
  out[row*CSd + tid] = d*rs*g[tid] + b[tid];
}

// ------------- zn LN: pair_bias (half) + znt bf16 [i][c][j] -------------
__global__ __launch_bounds__(1024, 4) void k_lnz_pb(
    const float* __restrict__ z, const float* __restrict__ g, const float* __restrict__ b,
    const float* __restrict__ wpb, __half* __restrict__ pb, __hip_bfloat16* __restrict__ znt){
  __shared__ float Zt[64*129];       // 33024 B
  __shared__ float wpbht[8*129];     // [h][c] pad-129 (4-way max)
  __shared__ float gl[128], bl[128];
  int tid = threadIdx.x;
  size_t row0 = (size_t)blockIdx.x*64;
  int ib = (int)(row0 >> 9), j0 = (int)(row0 & 511);
  {
    int c = tid>>3, h = tid&7;
    wpbht[h*129 + c] = wpb[tid];
  }
  if (tid < 128){ gl[tid] = g[tid]; bl[tid] = b[tid]; }
  // phase 1: each wave loads one row (512B) per iter as float2
  {
    int w = tid>>6, lane = tid&63;
    #pragma unroll
    for (int it=0; it<4; it++){
      int row = it*16 + w;
      const float2 v = *(const float2*)(z + (row0+row)*(size_t)CZd + lane*2);
      Zt[row*129 + lane*2]     = v.x;
      Zt[row*129 + lane*2 + 1] = v.y;
    }
  }
  __syncthreads();
  // phase 2: stats + in-place normalize + pb (register-resident)
  {
    int r = tid>>4, q = tid&15;
    int rot = 2*(q>>2);
    float S1=0.f, S2=0.f;
    float zv[8];
    #pragma unroll
    for (int i=0; i<8; i++){
      int ii = (i + rot) & 7;
      float v = Zt[r*129 + q*8 + ii];
      zv[i] = v;
      S1 += v; S2 += v*v;
    }
    S1 += __shfl_xor(S1,1); S2 += __shfl_xor(S2,1);
    S1 += __shfl_xor(S1,2); S2 += __shfl_xor(S2,2);
    S1 += __shfl_xor(S1,4); S2 += __shfl_xor(S2,4);
    S1 += __shfl_xor(S1,8); S2 += __shfl_xor(S2,8);
    float mu = S1 * (1.f/128.f);
    float var = S2 * (1.f/128.f) - mu*mu;
    float rs = rsqrtf(var + 1e-5f);
    float d[8] = {};
    #pragma unroll
    for (int i=0; i<8; i++){
      int ii = (i + rot) & 7;
      int c = q*8 + ii;
      float znv = (zv[i]-mu)*rs*gl[c] + bl[c];
      Zt[r*129 + c] = znv;
      #pragma unroll
      for (int h=0; h<8; h++) d[h] += znv * wpbht[h*129 + c];
    }
    #pragma unroll
    for (int h=0; h<8; h++){
      d[h] += __shfl_xor(d[h],1);
      d[h] += __shfl_xor(d[h],2);
      d[h] += __shfl_xor(d[h],4);
      d[h] += __shfl_xor(d[h],8);
    }
    if (q == 0){
      #pragma unroll
      for (int h=0; h<8; h++)
        pb[((size_t)(h*Lq + ib))*Lq + j0 + r] = __float2half(d[h]);
    }
  }
  __syncthreads();
  // phase 3: repack; thread (c = tid>>3, jg = tid&7) packs 8 j -> one dwordx4 store
  {
    int c = tid>>3, jg = tid&7;
    int jb = jg*8;
    unsigned int o[4];
    #pragma unroll
    for (int k=0; k<4; k++){
      float z0 = Zt[(jb+2*k)*129 + c];
      float z1 = Zt[(jb+2*k+1)*129 + c];
      o[k] = ((unsigned int)(unsigned short)f2bf(z0)) |
             (((unsigned int)(unsigned short)f2bf(z1)) << 16);
    }
    unsigned short* zo = (unsigned short*)znt;
    uint4 pk = make_uint4(o[0],o[1],o[2],o[3]);
    *(uint4*)(zo + ((size_t)(ib*128 + c))*512 + j0 + jb) = pk;
  }
}

// ------------- pack Q'/K'/V' in MFMA layouts (vectorized), compute qn/kn -------------
__global__ __launch_bounds__(256) void k_packqkv(
    const float* __restrict__ P, const float* __restrict__ R, const float* __restrict__ t,
    const float* __restrict__ gamma, int zfill,
    float* __restrict__ Qp, __hip_bfloat16* __restrict__ Kp, __hip_bfloat16* __restrict__ Vp,
    float* __restrict__ qn, float* __restrict__ kn){
  int idx = blockIdx.x*256 + threadIdx.x;   // 3*32768
  int region = idx >> 15;
  int rem = idx & 32767;
  if (region == 0){
    int oct = rem & 7, h = (rem>>3)&7, j = rem>>6;
    float v[8] = {0.f,0.f,0.f,0.f,0.f,0.f,0.f,0.f};
    const float* Prow = P + (size_t)j*NPROJ;
    if (oct < 4){
      float4 a = *(const float4*)(Prow + 256 + h*CHd + oct*8);
      float4 b4 = *(const float4*)(Prow + 256 + h*CHd + oct*8 + 4);
      v[0]=a.x; v[1]=a.y; v[2]=a.z; v[3]=a.w; v[4]=b4.x; v[5]=b4.y; v[6]=b4.z; v[7]=b4.w;
    } else if (oct < 6){
      const float* kp = Prow + 864 + h*12;
      float4 k0 = *(const float4*)kp;
      float4 k1 = *(const float4*)(kp+4);
      float4 k2 = *(const float4*)(kp+8);
      float kv[12] = {k0.x,k0.y,k0.z,k0.w,k1.x,k1.y,k1.z,k1.w,k2.x,k2.y,k2.z,k2.w};
      float Rl[9];
      #pragma unroll
      for (int ii=0; ii<9; ii++) Rl[ii] = R[j*9+ii];
      float tv[3] = {t[j*3], t[j*3+1], t[j*3+2]};
      float gvals[12];
      #pragma unroll
      for (int p=0; p<4; p++)
        #pragma unroll
        for (int ax=0; ax<3; ax++)
          gvals[p*3+ax] = Rl[ax*3]*kv[p*3] + Rl[ax*3+1]*kv[p*3+1] + Rl[ax*3+2]*kv[p*3+2] + tv[ax];
      if (oct == 4){
        #pragma unroll
        for (int m=0; m<8; m++) v[m] = gvals[m];
      } else {
        #pragma unroll
        for (int m=0; m<4; m++) v[m] = gvals[8+m];
        float acc = 0.f;
        #pragma unroll
        for (int m=0; m<12; m++) acc += gvals[m]*gvals[m];
        kn[j*Hd + h] = acc;
      }
    } else {
      if (!zfill) return;
    }
    shortx8 hi, lo;
    #pragma unroll
    for (int m=0; m<8; m++){
      short hh = f2bf(v[m]);
      hi[m] = hh; lo[m] = f2bf(v[m] - bf2f(hh));
    }
    int kc = oct>>2, jt = j>>4, l16 = j&15, quad = oct&3;
    size_t base = (size_t)((h*2+kc)*32 + jt)*1024 + (quad*16+l16)*8;
    short* kp16 = (short*)Kp;
    *(shortx8*)(kp16 + base)       = hi;
    *(shortx8*)(kp16 + base + 512) = lo;
  } else if (region == 1){
    int n = rem & 63, h = (rem>>6)&7, jg = rem>>9;
    int jb = jg*8;
    float v[8] = {0.f,0.f,0.f,0.f,0.f,0.f,0.f,0.f};
    if (n < 32){
      #pragma unroll
      for (int m=0; m<8; m++) v[m] = P[(size_t)(jb+m)*NPROJ + 512 + h*CHd + n];
    } else if (n < 56){
      int p = (n-32)/3, ax = (n-32)%3;
      #pragma unroll
      for (int m=0; m<8; m++){
        int j = jb+m;
        const float* vp = P + (size_t)j*NPROJ + 960 + h*24 + p*3;
        const float* Rr = R + j*9 + ax*3;
        v[m] = Rr[0]*vp[0] + Rr[1]*vp[1] + Rr[2]*vp[2] + t[j*3+ax];
      }
    } else {
      if (!zfill) return;
    }
    shortx8 hi, lo;
    #pragma unroll
    for (int m=0; m<8; m++){
      short hh = f2bf(v[m]);
      hi[m] = hh; lo[m] = f2bf(v[m] - bf2f(hh));
    }
    int kc2 = jg>>2, w = n>>4, l16 = n&15, quad = jg&3;
    size_t base = (size_t)((h*16+kc2)*4 + w)*1024 + (quad*16+l16)*8;
    short* vp16 = (short*)Vp;
    *(shortx8*)(vp16 + base)       = hi;
    *(shortx8*)(vp16 + base + 512) = lo;
  } else {
    int oct = rem & 7, h = (rem>>3)&7, i = rem>>6;
    float v[8] = {0.f,0.f,0.f,0.f,0.f,0.f,0.f,0.f};
    const float* Prow = P + (size_t)i*NPROJ;
    if (oct < 4){
      float4 a = *(const float4*)(Prow + h*CHd + oct*8);
      float4 b4 = *(const float4*)(Prow + h*CHd + oct*8 + 4);
      const float sc = WLC*ISC;
      v[0]=a.x*sc; v[1]=a.y*sc; v[2]=a.z*sc; v[3]=a.w*sc;
      v[4]=b4.x*sc; v[5]=b4.y*sc; v[6]=b4.z*sc; v[7]=b4.w*sc;
    } else if (oct < 6){
      const float* qp = Prow + 768 + h*12;
      float4 k0 = *(const float4*)qp;
      float4 k1 = *(const float4*)(qp+4);
      float4 k2 = *(const float4*)(qp+8);
      float kv[12] = {k0.x,k0.y,k0.z,k0.w,k1.x,k1.y,k1.z,k1.w,k2.x,k2.y,k2.z,k2.w};
      float Rl[9];
      #pragma unroll
      for (int ii=0; ii<9; ii++) Rl[ii] = R[i*9+ii];
      float tv[3] = {t[i*3], t[i*3+1], t[i*3+2]};
      float gvals[12];
      #pragma unroll
      for (int p=0; p<4; p++)
        #pragma unroll
        for (int ax=0; ax<3; ax++)
          gvals[p*3+ax] = Rl[ax*3]*kv[p*3] + Rl[ax*3+1]*kv[p*3+1] + Rl[ax*3+2]*kv[p*3+2] + tv[ax];
      float sc = WLC*WCC*gamma[h];
      if (oct == 4){
        #pragma unroll
        for (int m=0; m<8; m++) v[m] = gvals[m]*sc;
      } else {
        #pragma unroll
        for (int m=0; m<4; m++) v[m] = gvals[8+m]*sc;
        float acc = 0.f;
        #pragma unroll
        for (int m=0; m<12; m++) acc += gvals[m]*gvals[m];
        qn[i*Hd + h] = acc;
      }
    } else {
      if (!zfill) return;
    }
    float* qrow = Qp + ((size_t)h*512 + i)*64 + oct*8;
    *(float4*)qrow       = make_float4(v[0],v[1],v[2],v[3]);
    *(float4*)(qrow + 4) = make_float4(v[4],v[5],v[6],v[7]);
  }
}

// ------------- fused attention: 16 q-rows/block, 512 threads (8 waves) -------------
// LDS overlay: At (fp32 scores, 33KB) and AbfH/L (bf16 P fragments, 32KB) share the
// same buffer (At dead after softmax reads it into registers; barrier separates).
// LDS ~40KB -> 3-4 blocks/CU (24-32 waves) vs previous 16-wave 1-block 50% cap.
__global__ __launch_bounds__(512) void k_attn(
    const float* __restrict__ Qp, const __hip_bfloat16* __restrict__ Kp,
    const __hip_bfloat16* __restrict__ Vp,
    const float* __restrict__ qn, const float* __restrict__ kn,
    const __half* __restrict__ pb, const float* __restrict__ maskb,
    const float* __restrict__ gamma,
    const float* __restrict__ R, const float* __restrict__ t,
    __hip_bfloat16* __restrict__ a16hi,
    short* __restrict__ catA16){
  __shared__ char sbuf[16*516*4];     // At overlay AbfH(16KB)+AbfL(16KB)
  __shared__ float Pv[16][68];
  __shared__ float Ot[16][36];
  __shared__ float qnL[16];
  float (*At)[516] = (float(*)[516])sbuf;
  short* AbfH = (short*)sbuf;
  short* AbfL = (short*)(sbuf + 16384*2);   // note: 16384 shorts = 32768 B? keep 16KB each
  // AbfH occupies [0,16384)B, AbfL [16384,32768)B — fits inside 33024B At buffer
  AbfL = (short*)(sbuf + 16384);
  int tid = threadIdx.x;
  int i0 = blockIdx.x*16, h = blockIdx.y;
  int wave = tid>>6, lane = tid&63, quad = lane>>4, l16 = lane&15;
  int kg = wave>>2, ng = wave&3;
  float gam = gamma[h];
  float coef = 0.5f*WLC*WCC*gam;
  if (tid < 16) qnL[tid] = qn[(i0+tid)*Hd + h];
  __syncthreads();
  // Q fragments (16 real rows)
  const float* qrow = Qp + ((size_t)h*512 + i0 + l16)*64 + quad*8;
  shortx8 qhi[2], qlo[2];
  #pragma unroll
  for (int kc=0; kc<2; kc++){
    float4 v0 = *(const float4*)(qrow + kc*32);
    float4 v1 = *(const float4*)(qrow + kc*32 + 4);
    float av[8] = {v0.x,v0.y,v0.z,v0.w,v1.x,v1.y,v1.z,v1.w};
    #pragma unroll
    for (int j=0; j<8; j++){
      short hh = f2bf(av[j]);
      qhi[kc][j] = hh; qlo[kc][j] = f2bf(av[j] - bf2f(hh));
    }
  }
  // QK^T: 32 j-tiles over 8 waves, 4 iters
  #pragma unroll
  for (int it=0; it<4; it++){
    int jt = it*8 + wave;
    floatx4 acc = {};
    #pragma unroll
    for (int kc=0; kc<2; kc++){
      const __hip_bfloat16* bt = Kp + (size_t)((h*2+kc)*32 + jt)*1024 + lane*8;
      shortx8 bhi = *(const shortx8*)bt;
      shortx8 blo = *(const shortx8*)(bt + 512);
      acc = __builtin_amdgcn_mfma_f32_16x16x32_bf16(qhi[kc], bhi, acc, 0, 0, 0);
      acc = __builtin_amdgcn_mfma_f32_16x16x32_bf16(qlo[kc], bhi, acc, 0, 0, 0);
      acc = __builtin_amdgcn_mfma_f32_16x16x32_bf16(qhi[kc], blo, acc, 0, 0, 0);
    }
    int j = jt*16 + l16;
    float knj = kn[j*Hd + h];
    float mbj = maskb[j];
    #pragma unroll
    for (int r=0; r<4; r++){
      int i = quad*4 + r;
      float pbv = __half2float(pb[((size_t)(h*Lq) + i0 + i)*Lq + j]);
      At[i][j] = acc[r] + WLC*pbv + mbj - coef*(qnL[i] + knj);
    }
  }
  __syncthreads();
  // softmax: wave w owns rows w and w+8; read At into regs, then barrier, then
  // write Abf into the SAME LDS (overlay).
  float va[2][8];
  float inv[2];
  #pragma unroll
  for (int rr2=0; rr2<2; rr2++){
    int rr = wave + rr2*8;
    float m = -1e30f;
    #pragma unroll
    for (int k=0; k<8; k++){ va[rr2][k] = At[rr][lane + 64*k]; m = fmaxf(m, va[rr2][k]); }
    #pragma unroll
    for (int msk=32; msk; msk>>=1) m = fmaxf(m, __shfl_xor(m, msk));
    float ssum = 0.f;
    #pragma unroll
    for (int k=0; k<8; k++){ float e = __expf(va[rr2][k]-m); va[rr2][k]=e; ssum += e; }
    #pragma unroll
    for (int msk=32; msk; msk>>=1) ssum += __shfl_xor(ssum, msk);
    inv[rr2] = 1.f/ssum;
  }
  __syncthreads();   // all At reads complete before overlay writes
  #pragma unroll
  for (int rr2=0; rr2<2; rr2++){
    int rr = wave + rr2*8;
    #pragma unroll
    for (int k=0; k<8; k++){
      int cc = lane + 64*k;
      float p = va[rr2][k]*inv[rr2];
      short hh = f2bf(p);
      short ll = f2bf(p - bf2f(hh));
      a16hi[(((size_t)(i0+rr)*16 + (cc>>5))*8 + h)*32 + (cc&31)] = s2b(hh);
      int off = ((((cc>>5)*4 + ((cc>>3)&3))*16 + rr)<<3) + (cc&7);
      AbfH[off] = hh;
      AbfL[off] = ll;
    }
  }
  __syncthreads();
  // AV: wave (kg, ng): kg in {0,1} x 8 kc each; n-tile ng; one Pv partial plane
  floatx4 acc2 = {};
  #pragma unroll
  for (int kk=0; kk<8; kk++){
    int kc2 = kg*8 + kk;
    int aoff = (((kc2*4 + quad)*16 + l16))<<3;
    shortx8 ahi = *(const shortx8*)&AbfH[aoff];
    shortx8 alo = *(const shortx8*)&AbfL[aoff];
    const __hip_bfloat16* bt = Vp + (size_t)((h*16+kc2)*4 + ng)*1024 + lane*8;
    shortx8 bhi = *(const shortx8*)bt;
    shortx8 blo = *(const shortx8*)(bt + 512);
    acc2 = __builtin_amdgcn_mfma_f32_16x16x32_bf16(ahi, bhi, acc2, 0, 0, 0);
    acc2 = __builtin_amdgcn_mfma_f32_16x16x32_bf16(alo, bhi, acc2, 0, 0, 0);
    acc2 = __builtin_amdgcn_mfma_f32_16x16x32_bf16(ahi, blo, acc2, 0, 0, 0);
  }
  if (kg == 1){
    #pragma unroll
    for (int r=0;r<4;r++) Pv[quad*4+r][ng*16+l16] = acc2[r];
  }
  __syncthreads();
  if (kg == 0){
    int n = ng*16 + l16;
    #pragma unroll
    for (int r=0;r<4;r++){
      int i = quad*4+r;
      float v = acc2[r] + Pv[i][n];
      if (n < 32) cat_store(catA16, h*CHd + n, i0+i, v);
      else        Ot[i][n-32] = v;
    }
  }
  __syncthreads();
  if (tid < 128){
    int i = tid>>3, p = tid&7, gi = i0+i;
    float o0 = Ot[i][p*3], o1 = Ot[i][p*3+1], o2 = Ot[i][p*3+2];
    float d0 = o0 - t[gi*3], d1 = o1 - t[gi*3+1], d2 = o2 - t[gi*3+2];
    const float* Rm = R + gi*9;
    float l0 = Rm[0]*d0 + Rm[3]*d1 + Rm[6]*d2;
    float l1 = Rm[1]*d0 + Rm[4]*d1 + Rm[7]*d2;
    float l2 = Rm[2]*d0 + Rm[5]*d1 + Rm[8]*d2;
    int kb = 256 + h*24 + p*3;
    cat_store(catA16, kb,   gi, l0);
    cat_store(catA16, kb+1, gi, l1);
    cat_store(catA16, kb+2, gi, l2);
    cat_store(catA16, 448 + h*8 + p, gi, sqrtf(l0*l0 + l1*l1 + l2*l2 + 1e-8f));
  }
}

// ------------- opair = a @ zn via MFMA (a hi-only), 512 threads -------------
__global__ __launch_bounds__(512) void k_opair_mfma(
    const __hip_bfloat16* __restrict__ a16hi,
    const __hip_bfloat16* __restrict__ znt, short* __restrict__ catA16){
  int i = blockIdx.x;
  int tid = threadIdx.x;
  int wave = tid>>6, lane = tid&63, quad = lane>>4, l16 = lane&15;
  int nt = wave;
  floatx4 acc = {};
  const __hip_bfloat16* abase_h = a16hi + ((size_t)i*16*8 + (l16&7))*32 + quad*8;
  const __hip_bfloat16* zb = znt + ((size_t)i*128 + nt*16 + l16)*512 + quad*8;
  #pragma unroll
  for (int kt=0; kt<16; kt++){
    shortx8 ah = *(const shortx8*)(abase_h + kt*256);
    shortx8 b0 = *(const shortx8*)(zb + kt*32);
    acc = __builtin_amdgcn_mfma_f32_16x16x32_bf16(ah, b0, acc, 0, 0, 0);
  }
  if (quad < 2){
    #pragma unroll
    for (int r=0; r<4; r++){
      int h = quad*4 + r;
      cat_store(catA16, 512 + h*CZd + nt*16 + l16, i, acc[r]);
    }
  }
}

// ------------- mega: LN + 3 GEMMs + LN + upd + frame update (1024 threads) ---------
__device__ __forceinline__ void gemm_bf16w(
    const short* __restrict__ AHp, const short* __restrict__ ALp,
    short* __restrict__ OH, short* __restrict__ OL, float (*Yf)[260],
    const __hip_bfloat16* __restrict__ Wp, const float* __restrict__ bias,
    bool relu, int tid){
  int wave = tid>>6, lane = tid&63, quad = lane>>4, l16 = lane&15;
  floatx4 acc = {};
  #pragma unroll
  for (int kc=0; kc<8; kc++){
    int aoff = (((kc*4 + quad)*16 + l16))<<3;
    shortx8 ahi = *(const shortx8*)&AHp[aoff];
    shortx8 alo = *(const shortx8*)&ALp[aoff];
    const __hip_bfloat16* bt = Wp + (size_t)(kc*16 + wave)*1024 + lane*8;
    shortx8 bhi = *(const shortx8*)bt;
    shortx8 blo = *(const shortx8*)(bt + 512);
    acc = __builtin_amdgcn_mfma_f32_16x16x32_bf16(ahi, bhi, acc, 0, 0, 0);
    acc = __builtin_amdgcn_mfma_f32_16x16x32_bf16(alo, bhi, acc, 0, 0, 0);
    acc = __builtin_amdgcn_mfma_f32_16x16x32_bf16(ahi, blo, acc, 0, 0, 0);
  }
  int n = wave*16 + l16;
  float bs = bias[n];
  #pragma unroll
  for (int r=0;r<4;r++){
    float v = acc[r] + bs;
    if (relu) v = fmaxf(v, 0.f);
    int row = quad*4 + r;
    if (OH){
      short hh = f2bf(v);
      int off = ((((n>>5)*4 + ((n>>3)&3))*16 + row)<<3) + (n&7);
      OH[off] = hh;
      OL[off] = f2bf(v - bf2f(hh));
    } else {
      Yf[row][n] = v;
    }
  }
}

__global__ __launch_bounds__(1024) void k_mega(
    float* __restrict__ scb, const float* __restrict__ ipa,
    const float* __restrict__ gi_, const float* __restrict__ bi_,
    const __hip_bfloat16* __restrict__ W1, const float* __restrict__ c1,
    const __hip_bfloat16* __restrict__ W2, const float* __restrict__ c2,
    const __hip_bfloat16* __restrict__ W3, const float* __restrict__ c3,
    const float* __restrict__ gt_, const float* __restrict__ bt_,
    const float* __restrict__ mask,
    const float* __restrict__ wbb, const float* __restrict__ bbb,
    float* __restrict__ R, float* __restrict__ t, short* __restrict__ scA16){
  __shared__ float As[16][260], Bs[16][260];
  __shared__ short AH[2][4096], AL[2][4096];
  __shared__ float rA[16][33], rB[16][33];
  __shared__ float mv[16][2];
  __shared__ float u6p[16][6][2];
  int tid = threadIdx.x;
  int i0 = blockIdx.x*16;
  int r = (tid>>5)&15, c5 = tid&31, c0 = c5*8;
  float v[8];
  // stage 0: LN(sc + ipa0+ipa1+ipa2+ipa3)
  if (tid < 512){
    const float* sr = scb + (size_t)(i0+r)*CSd + c0;
    const float* p0 = ipa + (size_t)(i0+r)*CSd + c0;
    const float* p1 = p0 + 131072;
    const float* p2 = p0 + 262144;
    const float* p3 = p0 + 393216;
    float s1=0.f, s2=0.f;
    #pragma unroll
    for (int k2=0;k2<8;k2++){
      float x = sr[k2] + p0[k2] + p1[k2] + p2[k2] + p3[k2];
      v[k2]=x; s1+=x; s2+=x*x;
    }
    rA[r][c5]=s1; rB[r][c5]=s2;
  }
  __syncthreads();
  if (tid<16){
    float s1=0.f,s2=0.f;
    #pragma unroll
    for (int c=0;c<32;c++){ s1+=rA[tid][c]; s2+=rB[tid][c]; }
    float mu = s1*(1.f/CSd), var = s2*(1.f/CSd) - mu*mu;
    mv[tid][0]=mu; mv[tid][1]=rsqrtf(var+1e-5f);
  }
  __syncthreads();
  if (tid < 512){
    float mu=mv[r][0], rs=mv[r][1];
    #pragma unroll
    for (int k2=0;k2<8;k2++){
      int col = c0+k2;
      float o = (v[k2]-mu)*rs*gi_[col] + bi_[col];
      As[r][col] = o;
      short hh = f2bf(o);
      int off = ((((col>>5)*4 + ((col>>3)&3))*16 + r)<<3) + (col&7);
      AH[0][off] = hh;
      AL[0][off] = f2bf(o - bf2f(hh));
    }
  }
  __syncthreads();
  gemm_bf16w(AH[0], AL[0], AH[1], AL[1], nullptr, W1, c1, true, tid);
  __syncthreads();
  gemm_bf16w(AH[1], AL[1], AH[0], AL[0], nullptr, W2, c2, true, tid);
  __syncthreads();
  gemm_bf16w(AH[0], AL[0], nullptr, nullptr, Bs, W3, c3, false, tid);
  __syncthreads();
  // stage 4: LN(sc_new + tr3*mask)
  if (tid < 512){
    float mk = mask[i0+r];
    float s1=0.f, s2=0.f;
    #pragma unroll
    for (int k2=0;k2<8;k2++){ float x = As[r][c0+k2] + Bs[r][c0+k2]*mk; v[k2]=x; s1+=x; s2+=x*x; }
    rA[r][c5]=s1; rB[r][c5]=s2;
  }
  __syncthreads();
  if (tid<16){
    float s1=0.f,s2=0.f;
    #pragma unroll
    for (int c=0;c<32;c++){ s1+=rA[tid][c]; s2+=rB[tid][c]; }
    float mu = s1*(1.f/CSd), var = s2*(1.f/CSd) - mu*mu;
    mv[tid][0]=mu; mv[tid][1]=rsqrtf(var+1e-5f);
  }
  __syncthreads();
  if (tid < 512){
    float mu=mv[r][0], rs=mv[r][1];
    float* out = scb + (size_t)(i0+r)*CSd + c0;
    shortx8 hi, lo;
    #pragma unroll
    for (int k2=0;k2<8;k2++){
      int col = c0+k2;
      float o = (v[k2]-mu)*rs*gt_[col] + bt_[col];
      As[r][col] = o;
      out[k2] = o;
      short hh = f2bf(o);
      hi[k2] = hh; lo[k2] = f2bf(o - bf2f(hh));
    }
    size_t off = ((size_t)((c5>>2)*512 + i0 + r)*4 + (c5&3))*8;
    *(shortx8*)(scA16 + off)          = hi;
    *(shortx8*)(scA16 + off + 131072) = lo;
  }
  __syncthreads();
  // stage 5: upd (192-thread k-split) + quat update
  if (tid < 192){
    int rr = tid/12, o = (tid%12)>>1, half = tid&1;
    float acc = half ? 0.f : bbb[o];
    int kb = half*128;
    for (int k2=kb; k2<kb+128; k2++) acc += As[rr][k2]*wbb[k2*6+o];
    u6p[rr][o][half] = acc;
  }
  __syncthreads();
  if (tid < 16){
    int gidx = i0 + tid;
    float uu[6];
    #pragma unroll
    for (int o=0;o<6;o++) uu[o] = u6p[tid][o][0] + u6p[tid][o][1];
    float bq = uu[0], cq = uu[1], dq = uu[2];
    float norm = sqrtf(1.f + bq*bq + cq*cq + dq*dq);
    float a = 1.f/norm, b_ = bq/norm, c_ = cq/norm, d_ = dq/norm;
    float dR[9];
    dR[0] = a*a + b_*b_ - c_*c_ - d_*d_; dR[1] = 2.f*(b_*c_ - a*d_); dR[2] = 2.f*(b_*d_ + a*c_);
    dR[3] = 2.f*(b_*c_ + a*d_); dR[4] = a*a - b_*b_ + c_*c_ - d_*d_; dR[5] = 2.f*(c_*d_ - a*b_);
    dR[6] = 2.f*(b_*d_ - a*c_); dR[7] = 2.f*(c_*d_ + a*b_); dR[8] = a*a - b_*b_ - c_*c_ + d_*d_;
    float mk = mask[gidx];
    float dt0 = uu[3]*mk, dt1 = uu[4]*mk, dt2 = uu[5]*mk;
    float Rm[9];
    #pragma unroll
    for (int ii=0; ii<9; ii++) Rm[ii] = R[gidx*9+ii];
    t[gidx*3]   += Rm[0]*dt0 + Rm[1]*dt1 + Rm[2]*dt2;
    t[gidx*3+1] += Rm[3]*dt0 + Rm[4]*dt1 + Rm[5]*dt2;
    t[gidx*3+2] += Rm[6]*dt0 + Rm[7]*dt1 + Rm[8]*dt2;
    #pragma unroll
    for (int ii=0; ii<3; ii++)
      #pragma unroll
      for (int jj=0; jj<3; jj++)
        R[gidx*9 + ii*3 + jj] = Rm[ii*3]*dR[jj] + Rm[ii*3+1]*dR[3+jj] + Rm[ii*3+2]*dR[6+jj];
  }
}

// ------------- final output write -------------
__global__ __launch_bounds__(256) void k_writeout(
    const float* __restrict__ sc, const float* __restrict__ R, const float* __restrict__ t,
    float* __restrict__ out){
  int idx = blockIdx.x*256 + threadIdx.x;
  if      (idx < 131072) out[idx] = sc[idx];
  else if (idx < 135680) out[idx] = R[idx-131072];
  else if (idx < 137216) out[idx] = t[idx-135680];
}

extern "C" void kernel_launch(void* const* d_in, const int* in_sizes, int n_in,
                              void* d_out, int out_size, void* d_ws, size_t ws_size,
                              hipStream_t stream){
  const float* s      = (const float*)d_in[0];
  const float* z      = (const float*)d_in[1];
  const float* mask   = (const float*)d_in[2];
  const float* ln_s_g = (const float*)d_in[3];
  const float* ln_s_b = (const float*)d_in[4];
  const float* ln_z_g = (const float*)d_in[5];
  const float* ln_z_b = (const float*)d_in[6];
  const float* w_init = (const float*)d_in[7];
  const float* b_init = (const float*)d_in[8];
  const float* ln_ipa_g = (const float*)d_in[9];
  const float* ln_ipa_b = (const float*)d_in[10];
  const float* ln_tr_g  = (const float*)d_in[11];
  const float* ln_tr_b  = (const float*)d_in[12];
  const float* wq = (const float*)d_in[13]; const float* bq = (const float*)d_in[14];
  const float* wk = (const float*)d_in[15]; const float* bk = (const float*)d_in[16];
  const float* wv = (const float*)d_in[17]; const float* bv = (const float*)d_in[18];
  const float* wqp = (const float*)d_in[19]; const float* bqp = (const float*)d_in[20];
  const float* wkp = (const float*)d_in[21]; const float* bkp = (const float*)d_in[22];
  const float* wvp = (const float*)d_in[23]; const float* bvp = (const float*)d_in[24];
  const float* wpb = (const float*)d_in[25];
  const float* head_w = (const float*)d_in[26];
  const float* wo = (const float*)d_in[27]; const float* bo = (const float*)d_in[28];
  const float* wt1 = (const float*)d_in[29]; const float* bt1 = (const float*)d_in[30];
  const float* wt2 = (const float*)d_in[31]; const float* bt2 = (const float*)d_in[32];
  const float* wt3 = (const float*)d_in[33]; const float* bt3 = (const float*)d_in[34];
  const float* wbb = (const float*)d_in[35]; const float* bbb = (const float*)d_in[36];

  float* W = (float*)d_ws;
  float* scb   = W + OFF_SC;
  __half*  pbb  = (__half*)(W + OFF_PB);
  float* Pb    = W + OFF_P;
  float* qnb   = W + OFF_QN;
  float* knb   = W + OFF_KN;
  __hip_bfloat16* a16hi = (__hip_bfloat16*)(W + OFF_A16);
  short* catA16 = (short*)(W + OFF_CAT);
  float* s0b   = W + OFF_S0;
  float* Rb    = W + OFF_R;
  float* tb    = W + OFF_T;
  float* gammab= W + OFF_GAMMA;
  float* maskb = W + OFF_MASKB;
  float* bcat  = W + OFF_BCAT;
  __hip_bfloat16* WinitP = (__hip_bfloat16*)(W + OFF_WINITP);
  __hip_bfloat16* Wt1P   = (__hip_bfloat16*)(W + OFF_WT1P);
  __hip_bfloat16* Wt2P   = (__hip_bfloat16*)(W + OFF_WT2P);
  __hip_bfloat16* Wt3P   = (__hip_bfloat16*)(W + OFF_WT3P);
  __hip_bfloat16* WoP    = (__hip_bfloat16*)(W + OFF_WOP);
  __hip_bfloat16* WcatP  = (__hip_bfloat16*)(W + OFF_WCATP);
  float* Qp = W + OFF_QP;
  __hip_bfloat16* Kp = (__hip_bfloat16*)(W + OFF_KP);
  __hip_bfloat16* Vp = (__hip_bfloat16*)(W + OFF_VP);
  short* scA16 = (short*)(W + OFF_SCA16);
  __hip_bfloat16* znt = (__hip_bfloat16*)(W + OFF_ZNT);

  k_setup<<<9, 256, 0, stream>>>(bq,bk,bv,bqp,bkp,bvp, head_w, mask, bcat, gammab, maskb, Rb, tb);
  // all weight packs in one launch: 294912 + 65536 + 393216 + 3*65536 = 950272 elems
  k_packall<<<3712, 256, 0, stream>>>(wq,wk,wv,wqp,wkp,wvp, w_init, wo, wt1, wt2, wt3,
                                      WcatP, WinitP, WoP, Wt1P, Wt2P, Wt3P);

  k_addln<<<Lq, 256, 0, stream>>>(s, nullptr, ln_s_g, ln_s_b, s0b);
  k_gemm_mfma<4><<<dim3(4,8), 256, 0, stream>>>(s0b, CSd, WinitP, CSd, b_init, scb, 0, nullptr);
  k_cvtA<<<64, 256, 0, stream>>>(scb, scA16);
  k_lnz_pb<<<Lq*Lq/64, 1024, 0, stream>>>(z, ln_z_g, ln_z_b, wpb, pbb, znt);

  for (int it=0; it<8; ++it){
    k_gemm_proj<<<dim3(72,8), 256, 0, stream>>>(scA16, WcatP, bcat, Pb);
    k_packqkv<<<384, 256, 0, stream>>>(Pb, Rb, tb, gammab, (it==0)?1:0,
                                       Qp, Kp, Vp, qnb, knb);
    k_attn<<<dim3(32,8), 512, 0, stream>>>(Qp, Kp, Vp, qnb, knb, pbb, maskb, gammab, Rb, tb,
                                           a16hi, catA16);
    k_opair_mfma<<<Lq, 512, 0, stream>>>(a16hi, znt, catA16);
    k_gemm_ipa<<<dim3(16,32), 256, 0, stream>>>(catA16, WoP, bo, Pb);
    k_mega<<<32, 1024, 0, stream>>>(scb, Pb, ln_ipa_g, ln_ipa_b,
                                    Wt1P, bt1, Wt2P, bt2, Wt3P, bt3,
                                    ln_tr_g, ln_tr_b, mask, wbb, bbb, Rb, tb, scA16);
  }
  k_writeout<<<536, 256, 0, stream>>>(scb, Rb, tb, (float*)d_out);
}